// Round 6
// baseline (192.480 us; speedup 1.0000x reference)
//
#include <hip/hip_runtime.h>
#include <hip/hip_bf16.h>

#define N_NODES 100000
#define N_EDGES 1600000
#define FEAT 128
#define NBINS 2048
#define BIN_NODES 49            // 2048*49 = 100352 >= 100000
#define PBLK 64                 // partition blocks
#define CHUNK (N_EDGES / PBLK)  // 25000 (exact)
#define CSR_MAX 1280            // per-bin edges: mean 784, +17 sigma

typedef __bf16 bf16x8 __attribute__((ext_vector_type(8)));
typedef unsigned short ushort8 __attribute__((ext_vector_type(8)));
typedef float f32x4 __attribute__((ext_vector_type(4)));

__device__ __forceinline__ unsigned short f2bf_bits(float f) {
    unsigned u = __builtin_bit_cast(unsigned, f);
    unsigned r = (u + 0x7fffu + ((u >> 16) & 1u)) >> 16;
    return (unsigned short)r;
}
__device__ __forceinline__ float bf_lo(unsigned u) {
    return __builtin_bit_cast(float, u << 16);
}
__device__ __forceinline__ float bf_hi(unsigned u) {
    return __builtin_bit_cast(float, u & 0xFFFF0000u);
}

// ---------------------------------------------------------------------------
// 1) x (fp32) -> xbf (bf16 bits)
// ---------------------------------------------------------------------------
__global__ void prep_kernel(const float* __restrict__ x, unsigned short* __restrict__ xbf) {
    int t = blockIdx.x * blockDim.x + threadIdx.x;
    if (t >= N_NODES * FEAT / 8) return;
    float4 a = ((const float4*)x)[t * 2];
    float4 b = ((const float4*)x)[t * 2 + 1];
    ushort8 u;
    u[0] = f2bf_bits(a.x); u[1] = f2bf_bits(a.y);
    u[2] = f2bf_bits(a.z); u[3] = f2bf_bits(a.w);
    u[4] = f2bf_bits(b.x); u[5] = f2bf_bits(b.y);
    u[6] = f2bf_bits(b.z); u[7] = f2bf_bits(b.w);
    ((ushort8*)xbf)[t] = u;
}

// ---------------------------------------------------------------------------
// 2) partition pass A: per-(block,bin) histogram. histm[bin*PBLK + blk]
// ---------------------------------------------------------------------------
__global__ __launch_bounds__(512) void partA_kernel(const int* __restrict__ ei,
                                                    int* __restrict__ histm) {
    __shared__ int h[NBINS];
    const int tid = threadIdx.x, b = blockIdx.x;
    for (int i = tid; i < NBINS; i += 512) h[i] = 0;
    __syncthreads();
    const int4* dsts = (const int4*)(ei + N_EDGES + b * CHUNK);
    for (int i = tid; i < CHUNK / 4; i += 512) {
        int4 d = dsts[i];
        atomicAdd(&h[d.x / BIN_NODES], 1);
        atomicAdd(&h[d.y / BIN_NODES], 1);
        atomicAdd(&h[d.z / BIN_NODES], 1);
        atomicAdd(&h[d.w / BIN_NODES], 1);
    }
    __syncthreads();
    for (int i = tid; i < NBINS; i += 512) histm[i * PBLK + b] = h[i];
}

// ---------------------------------------------------------------------------
// 3) in-place exclusive scan of histm (131072 ints; 1024 thr x 32 int4 each)
// ---------------------------------------------------------------------------
__global__ __launch_bounds__(1024) void scan_kernel(int* __restrict__ m) {
    __shared__ int wsum[16];
    const int t = threadIdx.x, lane = t & 63, wid = t >> 6;
    const int qbase = t * 32;  // int4 index
    int s = 0;
    #pragma unroll
    for (int i = 0; i < 32; ++i) {
        int4 v = ((const int4*)m)[qbase + i];
        s += v.x + v.y + v.z + v.w;
    }
    int incl = s;
    #pragma unroll
    for (int d = 1; d < 64; d <<= 1) {
        int up = __shfl_up(incl, d);
        if (lane >= d) incl += up;
    }
    if (lane == 63) wsum[wid] = incl;
    __syncthreads();
    if (t == 0) {
        int run = 0;
        #pragma unroll
        for (int i = 0; i < 16; ++i) { int v = wsum[i]; wsum[i] = run; run += v; }
    }
    __syncthreads();
    int excl = wsum[wid] + incl - s;
    #pragma unroll
    for (int i = 0; i < 32; ++i) {
        int4 v = ((const int4*)m)[qbase + i];
        int4 w;
        w.x = excl; excl += v.x;
        w.y = excl; excl += v.y;
        w.z = excl; excl += v.z;
        w.w = excl; excl += v.w;
        ((int4*)m)[qbase + i] = w;
    }
}

// ---------------------------------------------------------------------------
// 4) partition pass B: scatter packed (src | ln<<17) into block-private,
//    cursor-sequential regions of ebin.
// ---------------------------------------------------------------------------
__global__ __launch_bounds__(512) void partB_kernel(const int* __restrict__ ei,
                                                    const int* __restrict__ offm,
                                                    int* __restrict__ ebin) {
    __shared__ int cur[NBINS];
    const int tid = threadIdx.x, b = blockIdx.x;
    for (int i = tid; i < NBINS; i += 512) cur[i] = offm[i * PBLK + b];
    __syncthreads();
    const int4* srcs = (const int4*)(ei + b * CHUNK);
    const int4* dsts = (const int4*)(ei + N_EDGES + b * CHUNK);
    for (int i = tid; i < CHUNK / 4; i += 512) {
        int4 s4 = srcs[i];
        int4 d4 = dsts[i];
        int bin, ln, pos;
        bin = d4.x / BIN_NODES; ln = d4.x - bin * BIN_NODES;
        pos = atomicAdd(&cur[bin], 1); ebin[pos] = s4.x | (ln << 17);
        bin = d4.y / BIN_NODES; ln = d4.y - bin * BIN_NODES;
        pos = atomicAdd(&cur[bin], 1); ebin[pos] = s4.y | (ln << 17);
        bin = d4.z / BIN_NODES; ln = d4.z - bin * BIN_NODES;
        pos = atomicAdd(&cur[bin], 1); ebin[pos] = s4.z | (ln << 17);
        bin = d4.w / BIN_NODES; ln = d4.w - bin * BIN_NODES;
        pos = atomicAdd(&cur[bin], 1); ebin[pos] = s4.w | (ln << 17);
    }
}

// ---------------------------------------------------------------------------
// 5) per-bin aggregation: exact LDS CSR + gather-mean, 8 rows in flight/wave.
//    One block per bin (49 nodes); 2048 blocks -> 8 blocks/CU.
// ---------------------------------------------------------------------------
__global__ __launch_bounds__(256) void agg_kernel(
    const unsigned short* __restrict__ xbf, const int* __restrict__ offm,
    const int* __restrict__ ebin, unsigned short* __restrict__ xbarbf,
    int* __restrict__ degs) {
    __shared__ int lcnt[BIN_NODES];
    __shared__ int loff[BIN_NODES];
    __shared__ int lcur[BIN_NODES];
    __shared__ int lcsr[CSR_MAX];

    const int b = blockIdx.x, tid = threadIdx.x;
    int nb = N_NODES - b * BIN_NODES;
    if (nb <= 0) return;          // trailing empty bins
    if (nb > BIN_NODES) nb = BIN_NODES;
    const int start = offm[b * PBLK];
    const int end = (b == NBINS - 1) ? N_EDGES : offm[(b + 1) * PBLK];

    if (tid < BIN_NODES) lcnt[tid] = 0;
    __syncthreads();
    for (int i = start + tid; i < end; i += 256)
        atomicAdd(&lcnt[ebin[i] >> 17], 1);
    __syncthreads();

    const int lane = tid & 63, wave = tid >> 6;
    // exclusive scan of 49 counters in wave 0
    if (wave == 0) {
        int c = (lane < BIN_NODES) ? lcnt[lane] : 0;
        int incl = c;
        #pragma unroll
        for (int d = 1; d < 64; d <<= 1) {
            int up = __shfl_up(incl, d);
            if (lane >= d) incl += up;
        }
        if (lane < BIN_NODES) {
            loff[lane] = incl - c;
            lcur[lane] = incl - c;
        }
    }
    __syncthreads();

    for (int i = start + tid; i < end; i += 256) {
        int v = ebin[i];
        int pos = atomicAdd(&lcur[v >> 17], 1);
        lcsr[pos] = v & 0x1FFFF;
    }
    __syncthreads();

    const int g = lane >> 4, c = (lane & 15) * 8;
    for (int ln = wave; ln < nb; ln += 4) {
        const int deg = lcnt[ln];
        const int s0 = loff[ln];
        float acc[8];
        #pragma unroll
        for (int i = 0; i < 8; ++i) acc[i] = 0.f;
        for (int base = 0; base < deg; base += 8) {
            int j0 = base + g, j1 = j0 + 4;
            bool pA = j0 < deg, pB = j1 < deg;
            int sA = pA ? lcsr[s0 + j0] : lcsr[s0];
            int sB = pB ? lcsr[s0 + j1] : lcsr[s0];
            uint4 va = *(const uint4*)(xbf + (size_t)sA * FEAT + c);
            uint4 vb = *(const uint4*)(xbf + (size_t)sB * FEAT + c);
            if (pA) {
                acc[0] += bf_lo(va.x); acc[1] += bf_hi(va.x);
                acc[2] += bf_lo(va.y); acc[3] += bf_hi(va.y);
                acc[4] += bf_lo(va.z); acc[5] += bf_hi(va.z);
                acc[6] += bf_lo(va.w); acc[7] += bf_hi(va.w);
            }
            if (pB) {
                acc[0] += bf_lo(vb.x); acc[1] += bf_hi(vb.x);
                acc[2] += bf_lo(vb.y); acc[3] += bf_hi(vb.y);
                acc[4] += bf_lo(vb.z); acc[5] += bf_hi(vb.z);
                acc[6] += bf_lo(vb.w); acc[7] += bf_hi(vb.w);
            }
        }
        #pragma unroll
        for (int i = 0; i < 8; ++i) {
            acc[i] += __shfl_xor(acc[i], 16);
            acc[i] += __shfl_xor(acc[i], 32);
        }
        const int n = b * BIN_NODES + ln;
        if (lane < 16) {
            float inv = 1.0f / (float)(deg > 0 ? deg : 1);
            ushort8 o;
            #pragma unroll
            for (int i = 0; i < 8; ++i) o[i] = f2bf_bits(acc[i] * inv);
            *(ushort8*)(xbarbf + (size_t)n * FEAT + c) = o;
        }
        if (lane == 0) degs[n] = deg;
    }
}

// ---------------------------------------------------------------------------
// 6) fused GEMM: out = xbar @ Wl^T + bl*[deg>0] + x @ Wr^T  (A already bf16)
// ---------------------------------------------------------------------------
__global__ __launch_bounds__(256) void gemm_kernel(
    const unsigned short* __restrict__ xbf, const unsigned short* __restrict__ xbarbf,
    const float* __restrict__ Wl, const float* __restrict__ bl,
    const float* __restrict__ Wr, const int* __restrict__ degs,
    float* __restrict__ out) {

    __shared__ unsigned short lM[32][136];
    __shared__ unsigned short lX[32][136];

    const int tid = threadIdx.x;
    const int wave = tid >> 6, lane = tid & 63;
    const int l15 = lane & 15, lhi = lane >> 4;
    const int colbase = wave * 32;

    bf16x8 bB[2][8];
    float biasv[2];
    #pragma unroll
    for (int ct = 0; ct < 2; ++ct) {
        int col = colbase + ct * 16 + l15;
        biasv[ct] = bl[col];
        const float* wl = Wl + (size_t)col * 128;
        const float* wr = Wr + (size_t)col * 128;
        #pragma unroll
        for (int s = 0; s < 4; ++s) {
            int kb = lhi * 8 + s * 32;
            bf16x8 bfr, cfr;
            #pragma unroll
            for (int i = 0; i < 8; ++i) {
                bfr[i] = __builtin_bit_cast(__bf16, f2bf_bits(wl[kb + i]));
                cfr[i] = __builtin_bit_cast(__bf16, f2bf_bits(wr[kb + i]));
            }
            bB[ct][s] = bfr;
            bB[ct][4 + s] = cfr;
        }
    }

    const int ntiles = N_NODES / 32;
    for (int tile = blockIdx.x; tile < ntiles; tile += gridDim.x) {
        const int row0 = tile * 32;
        {
            int r = tid >> 3;
            int c0 = (tid & 7) * 16;
            const unsigned short* sm = xbarbf + (size_t)(row0 + r) * FEAT + c0;
            const unsigned short* sx = xbf + (size_t)(row0 + r) * FEAT + c0;
            *(ushort8*)&lM[r][c0]     = *(const ushort8*)(sm);
            *(ushort8*)&lM[r][c0 + 8] = *(const ushort8*)(sm + 8);
            *(ushort8*)&lX[r][c0]     = *(const ushort8*)(sx);
            *(ushort8*)&lX[r][c0 + 8] = *(const ushort8*)(sx + 8);
        }
        __syncthreads();

        f32x4 acc[2][2];
        #pragma unroll
        for (int rh = 0; rh < 2; ++rh)
            #pragma unroll
            for (int ct = 0; ct < 2; ++ct) acc[rh][ct] = (f32x4){0.f, 0.f, 0.f, 0.f};

        #pragma unroll
        for (int rh = 0; rh < 2; ++rh) {
            int arow = rh * 16 + l15;
            bf16x8 aM[4], aX[4];
            #pragma unroll
            for (int s = 0; s < 4; ++s) {
                aM[s] = __builtin_bit_cast(bf16x8, *(const ushort8*)&lM[arow][lhi * 8 + s * 32]);
                aX[s] = __builtin_bit_cast(bf16x8, *(const ushort8*)&lX[arow][lhi * 8 + s * 32]);
            }
            #pragma unroll
            for (int ct = 0; ct < 2; ++ct) {
                f32x4 a = acc[rh][ct];
                #pragma unroll
                for (int s = 0; s < 4; ++s)
                    a = __builtin_amdgcn_mfma_f32_16x16x32_bf16(aM[s], bB[ct][s], a, 0, 0, 0);
                #pragma unroll
                for (int s = 0; s < 4; ++s)
                    a = __builtin_amdgcn_mfma_f32_16x16x32_bf16(aX[s], bB[ct][4 + s], a, 0, 0, 0);
                acc[rh][ct] = a;
            }
        }

        #pragma unroll
        for (int rh = 0; rh < 2; ++rh)
            #pragma unroll
            for (int ct = 0; ct < 2; ++ct) {
                int col = colbase + ct * 16 + l15;
                #pragma unroll
                for (int j = 0; j < 4; ++j) {
                    int r = row0 + rh * 16 + lhi * 4 + j;
                    float bias = (degs[r] > 0) ? biasv[ct] : 0.f;
                    out[(size_t)r * FEAT + col] = acc[rh][ct][j] + bias;
                }
            }
        __syncthreads();
    }
}

extern "C" void kernel_launch(void* const* d_in, const int* in_sizes, int n_in,
                              void* d_out, int out_size, void* d_ws, size_t ws_size,
                              hipStream_t stream) {
    const float* x  = (const float*)d_in[0];
    const int*   ei = (const int*)d_in[1];
    const float* Wl = (const float*)d_in[2];
    const float* bl = (const float*)d_in[3];
    const float* Wr = (const float*)d_in[4];
    float* out = (float*)d_out;

    unsigned short* xbf    = (unsigned short*)d_ws;                  // 25.6 MB
    unsigned short* xbarbf = xbf + (size_t)N_NODES * FEAT;           // 25.6 MB
    int* degs  = (int*)(xbarbf + (size_t)N_NODES * FEAT);            // 400 KB
    int* histm = degs + N_NODES;                                     // 512 KB
    int* ebin  = histm + NBINS * PBLK;                               // 6.4 MB

    prep_kernel<<<(N_NODES * FEAT / 8 + 255) / 256, 256, 0, stream>>>(x, xbf);
    partA_kernel<<<PBLK, 512, 0, stream>>>(ei, histm);
    scan_kernel<<<1, 1024, 0, stream>>>(histm);
    partB_kernel<<<PBLK, 512, 0, stream>>>(ei, histm, ebin);
    agg_kernel<<<NBINS, 256, 0, stream>>>(xbf, histm, ebin, xbarbf, degs);
    gemm_kernel<<<1024, 256, 0, stream>>>(xbf, xbarbf, Wl, bl, Wr, degs, out);
}

// Round 7
// 152.256 us; speedup vs baseline: 1.2642x; 1.2642x over previous
//
#include <hip/hip_runtime.h>
#include <hip/hip_bf16.h>

#define N_NODES 100000
#define N_EDGES 1600000
#define FEAT 128
#define NBINS 2048
#define BIN_NODES 49            // 2048*49 = 100352 >= 100000
#define PBLK 64                 // partition blocks
#define CHUNK (N_EDGES / PBLK)  // 25000 (exact)
#define CSR_MAX 1280            // per-bin edges: mean 784, +17 sigma

typedef __bf16 bf16x8 __attribute__((ext_vector_type(8)));
typedef unsigned short ushort8 __attribute__((ext_vector_type(8)));
typedef float f32x4 __attribute__((ext_vector_type(4)));

__device__ __forceinline__ unsigned short f2bf_bits(float f) {
    unsigned u = __builtin_bit_cast(unsigned, f);
    unsigned r = (u + 0x7fffu + ((u >> 16) & 1u)) >> 16;
    return (unsigned short)r;
}
__device__ __forceinline__ float bf_lo(unsigned u) {
    return __builtin_bit_cast(float, u << 16);
}
__device__ __forceinline__ float bf_hi(unsigned u) {
    return __builtin_bit_cast(float, u & 0xFFFF0000u);
}

// ---------------------------------------------------------------------------
// 1) x (fp32) -> xbf (bf16 bits)
// ---------------------------------------------------------------------------
__global__ void prep_kernel(const float* __restrict__ x, unsigned short* __restrict__ xbf) {
    int t = blockIdx.x * blockDim.x + threadIdx.x;
    if (t >= N_NODES * FEAT / 8) return;
    float4 a = ((const float4*)x)[t * 2];
    float4 b = ((const float4*)x)[t * 2 + 1];
    ushort8 u;
    u[0] = f2bf_bits(a.x); u[1] = f2bf_bits(a.y);
    u[2] = f2bf_bits(a.z); u[3] = f2bf_bits(a.w);
    u[4] = f2bf_bits(b.x); u[5] = f2bf_bits(b.y);
    u[6] = f2bf_bits(b.z); u[7] = f2bf_bits(b.w);
    ((ushort8*)xbf)[t] = u;
}

// ---------------------------------------------------------------------------
// 2) partition pass A: per-(block,bin) histogram. histm[bin*PBLK + blk]
// ---------------------------------------------------------------------------
__global__ __launch_bounds__(256) void partA_kernel(const int* __restrict__ ei,
                                                    int* __restrict__ histm) {
    __shared__ int h[NBINS];
    const int tid = threadIdx.x, b = blockIdx.x;
    for (int i = tid; i < NBINS; i += 256) h[i] = 0;
    __syncthreads();
    const int4* dsts = (const int4*)(ei + N_EDGES + b * CHUNK);
    for (int i = tid; i < CHUNK / 4; i += 256) {
        int4 d = dsts[i];
        atomicAdd(&h[d.x / BIN_NODES], 1);
        atomicAdd(&h[d.y / BIN_NODES], 1);
        atomicAdd(&h[d.z / BIN_NODES], 1);
        atomicAdd(&h[d.w / BIN_NODES], 1);
    }
    __syncthreads();
    for (int i = tid; i < NBINS; i += 256) histm[i * PBLK + b] = h[i];
}

// ---------------------------------------------------------------------------
// 3a) bin totals: one wave per bin reduces its 64 per-block counts
// ---------------------------------------------------------------------------
__global__ __launch_bounds__(256) void scanT_kernel(const int* __restrict__ histm,
                                                    int* __restrict__ T) {
    const int bin = blockIdx.x * 4 + (threadIdx.x >> 6);
    const int lane = threadIdx.x & 63;
    int v = histm[bin * PBLK + lane];
    #pragma unroll
    for (int d = 1; d < 64; d <<= 1) v += __shfl_xor(v, d);
    if (lane == 0) T[bin] = v;
}

// ---------------------------------------------------------------------------
// 3b) exclusive scan of 2048 bin totals (single block, 1024 thr, 2 each)
// ---------------------------------------------------------------------------
__global__ __launch_bounds__(1024) void scanB_kernel(const int* __restrict__ T,
                                                     int* __restrict__ binstart) {
    __shared__ int wsum[16];
    const int t = threadIdx.x, lane = t & 63, wid = t >> 6;
    const int a = T[2 * t], b = T[2 * t + 1];
    const int s = a + b;
    int incl = s;
    #pragma unroll
    for (int d = 1; d < 64; d <<= 1) {
        int up = __shfl_up(incl, d);
        if (lane >= d) incl += up;
    }
    if (lane == 63) wsum[wid] = incl;
    __syncthreads();
    if (t == 0) {
        int run = 0;
        #pragma unroll
        for (int i = 0; i < 16; ++i) { int v = wsum[i]; wsum[i] = run; run += v; }
    }
    __syncthreads();
    const int excl = wsum[wid] + incl - s;
    binstart[2 * t] = excl;
    binstart[2 * t + 1] = excl + a;
}

// ---------------------------------------------------------------------------
// 3c) per-(bin,blk) offsets: wave-prefix + binstart, in place
// ---------------------------------------------------------------------------
__global__ __launch_bounds__(256) void scanC_kernel(int* __restrict__ histm,
                                                    const int* __restrict__ binstart) {
    const int bin = blockIdx.x * 4 + (threadIdx.x >> 6);
    const int lane = threadIdx.x & 63;
    const int h = histm[bin * PBLK + lane];
    int incl = h;
    #pragma unroll
    for (int d = 1; d < 64; d <<= 1) {
        int up = __shfl_up(incl, d);
        if (lane >= d) incl += up;
    }
    histm[bin * PBLK + lane] = binstart[bin] + incl - h;
}

// ---------------------------------------------------------------------------
// 4) partition pass B: scatter packed (src | ln<<17) into block-private,
//    cursor-sequential regions of ebin.
// ---------------------------------------------------------------------------
__global__ __launch_bounds__(256) void partB_kernel(const int* __restrict__ ei,
                                                    const int* __restrict__ offm,
                                                    int* __restrict__ ebin) {
    __shared__ int cur[NBINS];
    const int tid = threadIdx.x, b = blockIdx.x;
    for (int i = tid; i < NBINS; i += 256) cur[i] = offm[i * PBLK + b];
    __syncthreads();
    const int4* srcs = (const int4*)(ei + b * CHUNK);
    const int4* dsts = (const int4*)(ei + N_EDGES + b * CHUNK);
    for (int i = tid; i < CHUNK / 4; i += 256) {
        int4 s4 = srcs[i];
        int4 d4 = dsts[i];
        int bin, ln, pos;
        bin = d4.x / BIN_NODES; ln = d4.x - bin * BIN_NODES;
        pos = atomicAdd(&cur[bin], 1); ebin[pos] = s4.x | (ln << 17);
        bin = d4.y / BIN_NODES; ln = d4.y - bin * BIN_NODES;
        pos = atomicAdd(&cur[bin], 1); ebin[pos] = s4.y | (ln << 17);
        bin = d4.z / BIN_NODES; ln = d4.z - bin * BIN_NODES;
        pos = atomicAdd(&cur[bin], 1); ebin[pos] = s4.z | (ln << 17);
        bin = d4.w / BIN_NODES; ln = d4.w - bin * BIN_NODES;
        pos = atomicAdd(&cur[bin], 1); ebin[pos] = s4.w | (ln << 17);
    }
}

// ---------------------------------------------------------------------------
// 5) per-bin aggregation: exact LDS CSR + gather-mean, 16 rows in flight/wave.
// ---------------------------------------------------------------------------
__global__ __launch_bounds__(256) void agg_kernel(
    const unsigned short* __restrict__ xbf, const int* __restrict__ offm,
    const int* __restrict__ ebin, unsigned short* __restrict__ xbarbf,
    int* __restrict__ degs) {
    __shared__ int lcnt[BIN_NODES];
    __shared__ int loff[BIN_NODES];
    __shared__ int lcur[BIN_NODES];
    __shared__ int lcsr[CSR_MAX];

    const int b = blockIdx.x, tid = threadIdx.x;
    int nb = N_NODES - b * BIN_NODES;
    if (nb <= 0) return;          // trailing empty bins
    if (nb > BIN_NODES) nb = BIN_NODES;
    const int start = offm[b * PBLK];
    const int end = (b == NBINS - 1) ? N_EDGES : offm[(b + 1) * PBLK];

    if (tid < BIN_NODES) lcnt[tid] = 0;
    __syncthreads();
    for (int i = start + tid; i < end; i += 256)
        atomicAdd(&lcnt[ebin[i] >> 17], 1);
    __syncthreads();

    const int lane = tid & 63, wave = tid >> 6;
    // exclusive scan of 49 counters in wave 0
    if (wave == 0) {
        int c = (lane < BIN_NODES) ? lcnt[lane] : 0;
        int incl = c;
        #pragma unroll
        for (int d = 1; d < 64; d <<= 1) {
            int up = __shfl_up(incl, d);
            if (lane >= d) incl += up;
        }
        if (lane < BIN_NODES) {
            loff[lane] = incl - c;
            lcur[lane] = incl - c;
        }
    }
    __syncthreads();

    for (int i = start + tid; i < end; i += 256) {
        int v = ebin[i];
        int pos = atomicAdd(&lcur[v >> 17], 1);
        lcsr[pos] = v & 0x1FFFF;
    }
    __syncthreads();

    const int g = lane >> 4;
    const unsigned c = (lane & 15) * 8;
    for (int ln = wave; ln < nb; ln += 4) {
        const int deg = lcnt[ln];
        const int s0 = loff[ln];
        float acc[8];
        #pragma unroll
        for (int i = 0; i < 8; ++i) acc[i] = 0.f;
        int base = 0;
        const int full16 = deg & ~15;
        for (; base < full16; base += 16) {
            unsigned sA = (unsigned)lcsr[s0 + base + g];
            unsigned sB = (unsigned)lcsr[s0 + base + g + 4];
            unsigned sC = (unsigned)lcsr[s0 + base + g + 8];
            unsigned sD = (unsigned)lcsr[s0 + base + g + 12];
            uint4 va = *(const uint4*)(xbf + ((sA << 7) + c));
            uint4 vb = *(const uint4*)(xbf + ((sB << 7) + c));
            uint4 vc = *(const uint4*)(xbf + ((sC << 7) + c));
            uint4 vd = *(const uint4*)(xbf + ((sD << 7) + c));
            acc[0] += bf_lo(va.x); acc[1] += bf_hi(va.x);
            acc[2] += bf_lo(va.y); acc[3] += bf_hi(va.y);
            acc[4] += bf_lo(va.z); acc[5] += bf_hi(va.z);
            acc[6] += bf_lo(va.w); acc[7] += bf_hi(va.w);
            acc[0] += bf_lo(vb.x); acc[1] += bf_hi(vb.x);
            acc[2] += bf_lo(vb.y); acc[3] += bf_hi(vb.y);
            acc[4] += bf_lo(vb.z); acc[5] += bf_hi(vb.z);
            acc[6] += bf_lo(vb.w); acc[7] += bf_hi(vb.w);
            acc[0] += bf_lo(vc.x); acc[1] += bf_hi(vc.x);
            acc[2] += bf_lo(vc.y); acc[3] += bf_hi(vc.y);
            acc[4] += bf_lo(vc.z); acc[5] += bf_hi(vc.z);
            acc[6] += bf_lo(vc.w); acc[7] += bf_hi(vc.w);
            acc[0] += bf_lo(vd.x); acc[1] += bf_hi(vd.x);
            acc[2] += bf_lo(vd.y); acc[3] += bf_hi(vd.y);
            acc[4] += bf_lo(vd.z); acc[5] += bf_hi(vd.z);
            acc[6] += bf_lo(vd.w); acc[7] += bf_hi(vd.w);
        }
        for (; base < deg; base += 8) {
            int j0 = base + g, j1 = j0 + 4;
            bool pA = j0 < deg, pB = j1 < deg;
            unsigned sA = (unsigned)(pA ? lcsr[s0 + j0] : lcsr[s0]);
            unsigned sB = (unsigned)(pB ? lcsr[s0 + j1] : lcsr[s0]);
            uint4 va = *(const uint4*)(xbf + ((sA << 7) + c));
            uint4 vb = *(const uint4*)(xbf + ((sB << 7) + c));
            if (pA) {
                acc[0] += bf_lo(va.x); acc[1] += bf_hi(va.x);
                acc[2] += bf_lo(va.y); acc[3] += bf_hi(va.y);
                acc[4] += bf_lo(va.z); acc[5] += bf_hi(va.z);
                acc[6] += bf_lo(va.w); acc[7] += bf_hi(va.w);
            }
            if (pB) {
                acc[0] += bf_lo(vb.x); acc[1] += bf_hi(vb.x);
                acc[2] += bf_lo(vb.y); acc[3] += bf_hi(vb.y);
                acc[4] += bf_lo(vb.z); acc[5] += bf_hi(vb.z);
                acc[6] += bf_lo(vb.w); acc[7] += bf_hi(vb.w);
            }
        }
        #pragma unroll
        for (int i = 0; i < 8; ++i) {
            acc[i] += __shfl_xor(acc[i], 16);
            acc[i] += __shfl_xor(acc[i], 32);
        }
        const int n = b * BIN_NODES + ln;
        if (lane < 16) {
            float inv = 1.0f / (float)(deg > 0 ? deg : 1);
            ushort8 o;
            #pragma unroll
            for (int i = 0; i < 8; ++i) o[i] = f2bf_bits(acc[i] * inv);
            *(ushort8*)(xbarbf + (size_t)n * FEAT + c) = o;
        }
        if (lane == 0) degs[n] = deg;
    }
}

// ---------------------------------------------------------------------------
// 6) fused GEMM: out = xbar @ Wl^T + bl*[deg>0] + x @ Wr^T  (A already bf16)
// ---------------------------------------------------------------------------
__global__ __launch_bounds__(256) void gemm_kernel(
    const unsigned short* __restrict__ xbf, const unsigned short* __restrict__ xbarbf,
    const float* __restrict__ Wl, const float* __restrict__ bl,
    const float* __restrict__ Wr, const int* __restrict__ degs,
    float* __restrict__ out) {

    __shared__ unsigned short lM[32][136];
    __shared__ unsigned short lX[32][136];

    const int tid = threadIdx.x;
    const int wave = tid >> 6, lane = tid & 63;
    const int l15 = lane & 15, lhi = lane >> 4;
    const int colbase = wave * 32;

    bf16x8 bB[2][8];
    float biasv[2];
    #pragma unroll
    for (int ct = 0; ct < 2; ++ct) {
        int col = colbase + ct * 16 + l15;
        biasv[ct] = bl[col];
        const float* wl = Wl + (size_t)col * 128;
        const float* wr = Wr + (size_t)col * 128;
        #pragma unroll
        for (int s = 0; s < 4; ++s) {
            int kb = lhi * 8 + s * 32;
            bf16x8 bfr, cfr;
            #pragma unroll
            for (int i = 0; i < 8; ++i) {
                bfr[i] = __builtin_bit_cast(__bf16, f2bf_bits(wl[kb + i]));
                cfr[i] = __builtin_bit_cast(__bf16, f2bf_bits(wr[kb + i]));
            }
            bB[ct][s] = bfr;
            bB[ct][4 + s] = cfr;
        }
    }

    const int ntiles = N_NODES / 32;
    for (int tile = blockIdx.x; tile < ntiles; tile += gridDim.x) {
        const int row0 = tile * 32;
        {
            int r = tid >> 3;
            int c0 = (tid & 7) * 16;
            const unsigned short* sm = xbarbf + (size_t)(row0 + r) * FEAT + c0;
            const unsigned short* sx = xbf + (size_t)(row0 + r) * FEAT + c0;
            *(ushort8*)&lM[r][c0]     = *(const ushort8*)(sm);
            *(ushort8*)&lM[r][c0 + 8] = *(const ushort8*)(sm + 8);
            *(ushort8*)&lX[r][c0]     = *(const ushort8*)(sx);
            *(ushort8*)&lX[r][c0 + 8] = *(const ushort8*)(sx + 8);
        }
        __syncthreads();

        f32x4 acc[2][2];
        #pragma unroll
        for (int rh = 0; rh < 2; ++rh)
            #pragma unroll
            for (int ct = 0; ct < 2; ++ct) acc[rh][ct] = (f32x4){0.f, 0.f, 0.f, 0.f};

        #pragma unroll
        for (int rh = 0; rh < 2; ++rh) {
            int arow = rh * 16 + l15;
            bf16x8 aM[4], aX[4];
            #pragma unroll
            for (int s = 0; s < 4; ++s) {
                aM[s] = __builtin_bit_cast(bf16x8, *(const ushort8*)&lM[arow][lhi * 8 + s * 32]);
                aX[s] = __builtin_bit_cast(bf16x8, *(const ushort8*)&lX[arow][lhi * 8 + s * 32]);
            }
            #pragma unroll
            for (int ct = 0; ct < 2; ++ct) {
                f32x4 a = acc[rh][ct];
                #pragma unroll
                for (int s = 0; s < 4; ++s)
                    a = __builtin_amdgcn_mfma_f32_16x16x32_bf16(aM[s], bB[ct][s], a, 0, 0, 0);
                #pragma unroll
                for (int s = 0; s < 4; ++s)
                    a = __builtin_amdgcn_mfma_f32_16x16x32_bf16(aX[s], bB[ct][4 + s], a, 0, 0, 0);
                acc[rh][ct] = a;
            }
        }

        #pragma unroll
        for (int rh = 0; rh < 2; ++rh)
            #pragma unroll
            for (int ct = 0; ct < 2; ++ct) {
                int col = colbase + ct * 16 + l15;
                #pragma unroll
                for (int j = 0; j < 4; ++j) {
                    int r = row0 + rh * 16 + lhi * 4 + j;
                    float bias = (degs[r] > 0) ? biasv[ct] : 0.f;
                    out[(size_t)r * FEAT + col] = acc[rh][ct][j] + bias;
                }
            }
        __syncthreads();
    }
}

extern "C" void kernel_launch(void* const* d_in, const int* in_sizes, int n_in,
                              void* d_out, int out_size, void* d_ws, size_t ws_size,
                              hipStream_t stream) {
    const float* x  = (const float*)d_in[0];
    const int*   ei = (const int*)d_in[1];
    const float* Wl = (const float*)d_in[2];
    const float* bl = (const float*)d_in[3];
    const float* Wr = (const float*)d_in[4];
    float* out = (float*)d_out;

    unsigned short* xbf    = (unsigned short*)d_ws;                  // 25.6 MB
    unsigned short* xbarbf = xbf + (size_t)N_NODES * FEAT;           // 25.6 MB
    int* degs     = (int*)(xbarbf + (size_t)N_NODES * FEAT);         // 400 KB
    int* histm    = degs + N_NODES;                                  // 512 KB
    int* T        = histm + NBINS * PBLK;                            // 8 KB
    int* binstart = T + NBINS;                                       // 8 KB
    int* ebin     = binstart + NBINS;                                // 6.4 MB

    prep_kernel<<<(N_NODES * FEAT / 8 + 255) / 256, 256, 0, stream>>>(x, xbf);
    partA_kernel<<<PBLK, 256, 0, stream>>>(ei, histm);
    scanT_kernel<<<NBINS / 4, 256, 0, stream>>>(histm, T);
    scanB_kernel<<<1, 1024, 0, stream>>>(T, binstart);
    scanC_kernel<<<NBINS / 4, 256, 0, stream>>>(histm, binstart);
    partB_kernel<<<PBLK, 256, 0, stream>>>(ei, histm, ebin);
    agg_kernel<<<NBINS, 256, 0, stream>>>(xbf, histm, ebin, xbarbf, degs);
    gemm_kernel<<<1024, 256, 0, stream>>>(xbf, xbarbf, Wl, bl, Wr, degs, out);
}

// Round 8
// 142.548 us; speedup vs baseline: 1.3503x; 1.0681x over previous
//
#include <hip/hip_runtime.h>
#include <hip/hip_bf16.h>

#define N_NODES 100000
#define N_EDGES 1600000
#define FEAT 128
#define NBINS 2048
#define BIN_NODES 49            // 2048*49 = 100352 >= 100000
#define PBLK 64                 // partition blocks
#define CHUNK (N_EDGES / PBLK)  // 25000 (exact)
#define CSR_MAX 1280            // per-bin edges: mean 784, +17 sigma

typedef __bf16 bf16x8 __attribute__((ext_vector_type(8)));
typedef unsigned short ushort8 __attribute__((ext_vector_type(8)));
typedef float f32x4 __attribute__((ext_vector_type(4)));
typedef float f32x2 __attribute__((ext_vector_type(2)));

__device__ __forceinline__ unsigned short f2bf_bits(float f) {
    unsigned u = __builtin_bit_cast(unsigned, f);
    unsigned r = (u + 0x7fffu + ((u >> 16) & 1u)) >> 16;
    return (unsigned short)r;
}

// ---------------------------------------------------------------------------
// 1) x (fp32) -> xbf (bf16 bits) AND x8 (fp8 e4m3, for the gather)
// ---------------------------------------------------------------------------
__global__ void prep_kernel(const float* __restrict__ x,
                            unsigned short* __restrict__ xbf,
                            unsigned int* __restrict__ x8) {
    int t = blockIdx.x * blockDim.x + threadIdx.x;
    if (t >= N_NODES * FEAT / 8) return;
    float4 a = ((const float4*)x)[t * 2];
    float4 b = ((const float4*)x)[t * 2 + 1];
    ushort8 u;
    u[0] = f2bf_bits(a.x); u[1] = f2bf_bits(a.y);
    u[2] = f2bf_bits(a.z); u[3] = f2bf_bits(a.w);
    u[4] = f2bf_bits(b.x); u[5] = f2bf_bits(b.y);
    u[6] = f2bf_bits(b.z); u[7] = f2bf_bits(b.w);
    ((ushort8*)xbf)[t] = u;
    int w0 = __builtin_amdgcn_cvt_pk_fp8_f32(a.x, a.y, 0, false);
    w0     = __builtin_amdgcn_cvt_pk_fp8_f32(a.z, a.w, w0, true);
    int w1 = __builtin_amdgcn_cvt_pk_fp8_f32(b.x, b.y, 0, false);
    w1     = __builtin_amdgcn_cvt_pk_fp8_f32(b.z, b.w, w1, true);
    uint2 p; p.x = (unsigned)w0; p.y = (unsigned)w1;
    ((uint2*)x8)[t] = p;
}

// ---------------------------------------------------------------------------
// 2) partition pass A: per-(block,bin) histogram. histm[bin*PBLK + blk]
// ---------------------------------------------------------------------------
__global__ __launch_bounds__(256) void partA_kernel(const int* __restrict__ ei,
                                                    int* __restrict__ histm) {
    __shared__ int h[NBINS];
    const int tid = threadIdx.x, b = blockIdx.x;
    for (int i = tid; i < NBINS; i += 256) h[i] = 0;
    __syncthreads();
    const int4* dsts = (const int4*)(ei + N_EDGES + b * CHUNK);
    for (int i = tid; i < CHUNK / 4; i += 256) {
        int4 d = dsts[i];
        atomicAdd(&h[d.x / BIN_NODES], 1);
        atomicAdd(&h[d.y / BIN_NODES], 1);
        atomicAdd(&h[d.z / BIN_NODES], 1);
        atomicAdd(&h[d.w / BIN_NODES], 1);
    }
    __syncthreads();
    for (int i = tid; i < NBINS; i += 256) histm[i * PBLK + b] = h[i];
}

// ---------------------------------------------------------------------------
// 3a) bin totals: one wave per bin reduces its 64 per-block counts
// ---------------------------------------------------------------------------
__global__ __launch_bounds__(256) void scanT_kernel(const int* __restrict__ histm,
                                                    int* __restrict__ T) {
    const int bin = blockIdx.x * 4 + (threadIdx.x >> 6);
    const int lane = threadIdx.x & 63;
    int v = histm[bin * PBLK + lane];
    #pragma unroll
    for (int d = 1; d < 64; d <<= 1) v += __shfl_xor(v, d);
    if (lane == 0) T[bin] = v;
}

// ---------------------------------------------------------------------------
// 3b) exclusive scan of 2048 bin totals (single block, 1024 thr, 2 each)
// ---------------------------------------------------------------------------
__global__ __launch_bounds__(1024) void scanB_kernel(const int* __restrict__ T,
                                                     int* __restrict__ binstart) {
    __shared__ int wsum[16];
    const int t = threadIdx.x, lane = t & 63, wid = t >> 6;
    const int a = T[2 * t], b = T[2 * t + 1];
    const int s = a + b;
    int incl = s;
    #pragma unroll
    for (int d = 1; d < 64; d <<= 1) {
        int up = __shfl_up(incl, d);
        if (lane >= d) incl += up;
    }
    if (lane == 63) wsum[wid] = incl;
    __syncthreads();
    if (t == 0) {
        int run = 0;
        #pragma unroll
        for (int i = 0; i < 16; ++i) { int v = wsum[i]; wsum[i] = run; run += v; }
    }
    __syncthreads();
    const int excl = wsum[wid] + incl - s;
    binstart[2 * t] = excl;
    binstart[2 * t + 1] = excl + a;
}

// ---------------------------------------------------------------------------
// 3c) per-(bin,blk) offsets: wave-prefix + binstart, in place
// ---------------------------------------------------------------------------
__global__ __launch_bounds__(256) void scanC_kernel(int* __restrict__ histm,
                                                    const int* __restrict__ binstart) {
    const int bin = blockIdx.x * 4 + (threadIdx.x >> 6);
    const int lane = threadIdx.x & 63;
    const int h = histm[bin * PBLK + lane];
    int incl = h;
    #pragma unroll
    for (int d = 1; d < 64; d <<= 1) {
        int up = __shfl_up(incl, d);
        if (lane >= d) incl += up;
    }
    histm[bin * PBLK + lane] = binstart[bin] + incl - h;
}

// ---------------------------------------------------------------------------
// 4) partition pass B: scatter packed (src | ln<<17) into block-private,
//    cursor-sequential regions of ebin.
// ---------------------------------------------------------------------------
__global__ __launch_bounds__(256) void partB_kernel(const int* __restrict__ ei,
                                                    const int* __restrict__ offm,
                                                    int* __restrict__ ebin) {
    __shared__ int cur[NBINS];
    const int tid = threadIdx.x, b = blockIdx.x;
    for (int i = tid; i < NBINS; i += 256) cur[i] = offm[i * PBLK + b];
    __syncthreads();
    const int4* srcs = (const int4*)(ei + b * CHUNK);
    const int4* dsts = (const int4*)(ei + N_EDGES + b * CHUNK);
    for (int i = tid; i < CHUNK / 4; i += 256) {
        int4 s4 = srcs[i];
        int4 d4 = dsts[i];
        int bin, ln, pos;
        bin = d4.x / BIN_NODES; ln = d4.x - bin * BIN_NODES;
        pos = atomicAdd(&cur[bin], 1); ebin[pos] = s4.x | (ln << 17);
        bin = d4.y / BIN_NODES; ln = d4.y - bin * BIN_NODES;
        pos = atomicAdd(&cur[bin], 1); ebin[pos] = s4.y | (ln << 17);
        bin = d4.z / BIN_NODES; ln = d4.z - bin * BIN_NODES;
        pos = atomicAdd(&cur[bin], 1); ebin[pos] = s4.z | (ln << 17);
        bin = d4.w / BIN_NODES; ln = d4.w - bin * BIN_NODES;
        pos = atomicAdd(&cur[bin], 1); ebin[pos] = s4.w | (ln << 17);
    }
}

// ---------------------------------------------------------------------------
// 5) per-bin aggregation: exact LDS CSR + fp8 gather-mean (128 B rows).
// ---------------------------------------------------------------------------
#define ACC8(v)                                                             \
    {                                                                       \
        f32x2 f0 = __builtin_amdgcn_cvt_pk_f32_fp8((int)(v).x, false);      \
        f32x2 f1 = __builtin_amdgcn_cvt_pk_f32_fp8((int)(v).x, true);       \
        f32x2 f2 = __builtin_amdgcn_cvt_pk_f32_fp8((int)(v).y, false);      \
        f32x2 f3 = __builtin_amdgcn_cvt_pk_f32_fp8((int)(v).y, true);       \
        acc[0] += f0[0]; acc[1] += f0[1];                                   \
        acc[2] += f1[0]; acc[3] += f1[1];                                   \
        acc[4] += f2[0]; acc[5] += f2[1];                                   \
        acc[6] += f3[0]; acc[7] += f3[1];                                   \
    }

__global__ __launch_bounds__(256) void agg_kernel(
    const unsigned char* __restrict__ x8, const int* __restrict__ offm,
    const int* __restrict__ ebin, unsigned short* __restrict__ xbarbf,
    int* __restrict__ degs) {
    __shared__ int lcnt[BIN_NODES];
    __shared__ int loff[BIN_NODES];
    __shared__ int lcur[BIN_NODES];
    __shared__ int lcsr[CSR_MAX];

    const int b = blockIdx.x, tid = threadIdx.x;
    int nb = N_NODES - b * BIN_NODES;
    if (nb <= 0) return;          // trailing empty bins
    if (nb > BIN_NODES) nb = BIN_NODES;
    const int start = offm[b * PBLK];
    const int end = (b == NBINS - 1) ? N_EDGES : offm[(b + 1) * PBLK];

    if (tid < BIN_NODES) lcnt[tid] = 0;
    __syncthreads();
    for (int i = start + tid; i < end; i += 256)
        atomicAdd(&lcnt[ebin[i] >> 17], 1);
    __syncthreads();

    const int lane = tid & 63, wave = tid >> 6;
    // exclusive scan of 49 counters in wave 0
    if (wave == 0) {
        int c = (lane < BIN_NODES) ? lcnt[lane] : 0;
        int incl = c;
        #pragma unroll
        for (int d = 1; d < 64; d <<= 1) {
            int up = __shfl_up(incl, d);
            if (lane >= d) incl += up;
        }
        if (lane < BIN_NODES) {
            loff[lane] = incl - c;
            lcur[lane] = incl - c;
        }
    }
    __syncthreads();

    for (int i = start + tid; i < end; i += 256) {
        int v = ebin[i];
        int pos = atomicAdd(&lcur[v >> 17], 1);
        lcsr[pos] = v & 0x1FFFF;
    }
    __syncthreads();

    const int g = lane >> 4;
    const unsigned c8 = (lane & 15) * 8;   // byte offset in 128 B fp8 row
    for (int ln = wave; ln < nb; ln += 4) {
        const int deg = lcnt[ln];
        const int s0 = loff[ln];
        float acc[8];
        #pragma unroll
        for (int i = 0; i < 8; ++i) acc[i] = 0.f;
        int base = 0;
        const int full16 = deg & ~15;
        for (; base < full16; base += 16) {
            unsigned sA = (unsigned)lcsr[s0 + base + g];
            unsigned sB = (unsigned)lcsr[s0 + base + g + 4];
            unsigned sC = (unsigned)lcsr[s0 + base + g + 8];
            unsigned sD = (unsigned)lcsr[s0 + base + g + 12];
            uint2 va = *(const uint2*)(x8 + ((sA << 7) + c8));
            uint2 vb = *(const uint2*)(x8 + ((sB << 7) + c8));
            uint2 vc = *(const uint2*)(x8 + ((sC << 7) + c8));
            uint2 vd = *(const uint2*)(x8 + ((sD << 7) + c8));
            ACC8(va); ACC8(vb); ACC8(vc); ACC8(vd);
        }
        for (; base < deg; base += 8) {
            int j0 = base + g, j1 = j0 + 4;
            bool pA = j0 < deg, pB = j1 < deg;
            unsigned sA = (unsigned)(pA ? lcsr[s0 + j0] : lcsr[s0]);
            unsigned sB = (unsigned)(pB ? lcsr[s0 + j1] : lcsr[s0]);
            uint2 va = *(const uint2*)(x8 + ((sA << 7) + c8));
            uint2 vb = *(const uint2*)(x8 + ((sB << 7) + c8));
            if (pA) ACC8(va);
            if (pB) ACC8(vb);
        }
        #pragma unroll
        for (int i = 0; i < 8; ++i) {
            acc[i] += __shfl_xor(acc[i], 16);
            acc[i] += __shfl_xor(acc[i], 32);
        }
        const int n = b * BIN_NODES + ln;
        if (lane < 16) {
            float inv = 1.0f / (float)(deg > 0 ? deg : 1);
            ushort8 o;
            #pragma unroll
            for (int i = 0; i < 8; ++i) o[i] = f2bf_bits(acc[i] * inv);
            *(ushort8*)(xbarbf + (size_t)n * FEAT + c8) = o;
        }
        if (lane == 0) degs[n] = deg;
    }
}

// ---------------------------------------------------------------------------
// 6) fused GEMM: out = xbar @ Wl^T + bl*[deg>0] + x @ Wr^T  (A already bf16)
// ---------------------------------------------------------------------------
__global__ __launch_bounds__(256) void gemm_kernel(
    const unsigned short* __restrict__ xbf, const unsigned short* __restrict__ xbarbf,
    const float* __restrict__ Wl, const float* __restrict__ bl,
    const float* __restrict__ Wr, const int* __restrict__ degs,
    float* __restrict__ out) {

    __shared__ unsigned short lM[32][136];
    __shared__ unsigned short lX[32][136];

    const int tid = threadIdx.x;
    const int wave = tid >> 6, lane = tid & 63;
    const int l15 = lane & 15, lhi = lane >> 4;
    const int colbase = wave * 32;

    bf16x8 bB[2][8];
    float biasv[2];
    #pragma unroll
    for (int ct = 0; ct < 2; ++ct) {
        int col = colbase + ct * 16 + l15;
        biasv[ct] = bl[col];
        const float* wl = Wl + (size_t)col * 128;
        const float* wr = Wr + (size_t)col * 128;
        #pragma unroll
        for (int s = 0; s < 4; ++s) {
            int kb = lhi * 8 + s * 32;
            bf16x8 bfr, cfr;
            #pragma unroll
            for (int i = 0; i < 8; ++i) {
                bfr[i] = __builtin_bit_cast(__bf16, f2bf_bits(wl[kb + i]));
                cfr[i] = __builtin_bit_cast(__bf16, f2bf_bits(wr[kb + i]));
            }
            bB[ct][s] = bfr;
            bB[ct][4 + s] = cfr;
        }
    }

    const int ntiles = N_NODES / 32;
    for (int tile = blockIdx.x; tile < ntiles; tile += gridDim.x) {
        const int row0 = tile * 32;
        {
            int r = tid >> 3;
            int c0 = (tid & 7) * 16;
            const unsigned short* sm = xbarbf + (size_t)(row0 + r) * FEAT + c0;
            const unsigned short* sx = xbf + (size_t)(row0 + r) * FEAT + c0;
            *(ushort8*)&lM[r][c0]     = *(const ushort8*)(sm);
            *(ushort8*)&lM[r][c0 + 8] = *(const ushort8*)(sm + 8);
            *(ushort8*)&lX[r][c0]     = *(const ushort8*)(sx);
            *(ushort8*)&lX[r][c0 + 8] = *(const ushort8*)(sx + 8);
        }
        __syncthreads();

        f32x4 acc[2][2];
        #pragma unroll
        for (int rh = 0; rh < 2; ++rh)
            #pragma unroll
            for (int ct = 0; ct < 2; ++ct) acc[rh][ct] = (f32x4){0.f, 0.f, 0.f, 0.f};

        #pragma unroll
        for (int rh = 0; rh < 2; ++rh) {
            int arow = rh * 16 + l15;
            bf16x8 aM[4], aX[4];
            #pragma unroll
            for (int s = 0; s < 4; ++s) {
                aM[s] = __builtin_bit_cast(bf16x8, *(const ushort8*)&lM[arow][lhi * 8 + s * 32]);
                aX[s] = __builtin_bit_cast(bf16x8, *(const ushort8*)&lX[arow][lhi * 8 + s * 32]);
            }
            #pragma unroll
            for (int ct = 0; ct < 2; ++ct) {
                f32x4 a = acc[rh][ct];
                #pragma unroll
                for (int s = 0; s < 4; ++s)
                    a = __builtin_amdgcn_mfma_f32_16x16x32_bf16(aM[s], bB[ct][s], a, 0, 0, 0);
                #pragma unroll
                for (int s = 0; s < 4; ++s)
                    a = __builtin_amdgcn_mfma_f32_16x16x32_bf16(aX[s], bB[ct][4 + s], a, 0, 0, 0);
                acc[rh][ct] = a;
            }
        }

        #pragma unroll
        for (int rh = 0; rh < 2; ++rh)
            #pragma unroll
            for (int ct = 0; ct < 2; ++ct) {
                int col = colbase + ct * 16 + l15;
                #pragma unroll
                for (int j = 0; j < 4; ++j) {
                    int r = row0 + rh * 16 + lhi * 4 + j;
                    float bias = (degs[r] > 0) ? biasv[ct] : 0.f;
                    out[(size_t)r * FEAT + col] = acc[rh][ct][j] + bias;
                }
            }
        __syncthreads();
    }
}

extern "C" void kernel_launch(void* const* d_in, const int* in_sizes, int n_in,
                              void* d_out, int out_size, void* d_ws, size_t ws_size,
                              hipStream_t stream) {
    const float* x  = (const float*)d_in[0];
    const int*   ei = (const int*)d_in[1];
    const float* Wl = (const float*)d_in[2];
    const float* bl = (const float*)d_in[3];
    const float* Wr = (const float*)d_in[4];
    float* out = (float*)d_out;

    unsigned short* xbf    = (unsigned short*)d_ws;                  // 25.6 MB
    unsigned short* xbarbf = xbf + (size_t)N_NODES * FEAT;           // 25.6 MB
    unsigned int* x8       = (unsigned int*)(xbarbf + (size_t)N_NODES * FEAT); // 12.8 MB
    int* degs     = (int*)(x8 + (size_t)N_NODES * FEAT / 4);         // 400 KB
    int* histm    = degs + N_NODES;                                  // 512 KB
    int* T        = histm + NBINS * PBLK;                            // 8 KB
    int* binstart = T + NBINS;                                       // 8 KB
    int* ebin     = binstart + NBINS;                                // 6.4 MB

    prep_kernel<<<(N_NODES * FEAT / 8 + 255) / 256, 256, 0, stream>>>(x, xbf, x8);
    partA_kernel<<<PBLK, 256, 0, stream>>>(ei, histm);
    scanT_kernel<<<NBINS / 4, 256, 0, stream>>>(histm, T);
    scanB_kernel<<<1, 1024, 0, stream>>>(T, binstart);
    scanC_kernel<<<NBINS / 4, 256, 0, stream>>>(histm, binstart);
    partB_kernel<<<PBLK, 256, 0, stream>>>(ei, histm, ebin);
    agg_kernel<<<NBINS, 256, 0, stream>>>((const unsigned char*)x8, histm, ebin, xbarbf, degs);
    gemm_kernel<<<1024, 256, 0, stream>>>(xbf, xbarbf, Wl, bl, Wr, degs, out);
}

// Round 9
// 115.995 us; speedup vs baseline: 1.6594x; 1.2289x over previous
//
#include <hip/hip_runtime.h>
#include <hip/hip_bf16.h>

#define N_NODES 100000
#define N_EDGES 1600000
#define FEAT 128
#define NBINS 2048
#define BIN_NODES 49            // 2048*49 = 100352 >= 100000
#define PBLK 250                // partition blocks (each owns CHUNK edges)
#define CHUNK (N_EDGES / PBLK)  // 6400 (exact)
#define NTBL (NBINS + 1)
#define CSR_MAX 1280            // per-bin edges: mean 784, +17 sigma

typedef __bf16 bf16x8 __attribute__((ext_vector_type(8)));
typedef unsigned short ushort8 __attribute__((ext_vector_type(8)));
typedef float f32x4 __attribute__((ext_vector_type(4)));
typedef float f32x2 __attribute__((ext_vector_type(2)));

__device__ __forceinline__ unsigned short f2bf_bits(float f) {
    unsigned u = __builtin_bit_cast(unsigned, f);
    unsigned r = (u + 0x7fffu + ((u >> 16) & 1u)) >> 16;
    return (unsigned short)r;
}

// ---------------------------------------------------------------------------
// 1) x (fp32) -> xbf (bf16 bits) AND x8 (fp8 e4m3, for the gather)
// ---------------------------------------------------------------------------
__global__ void prep_kernel(const float* __restrict__ x,
                            unsigned short* __restrict__ xbf,
                            unsigned int* __restrict__ x8) {
    int t = blockIdx.x * blockDim.x + threadIdx.x;
    if (t >= N_NODES * FEAT / 8) return;
    float4 a = ((const float4*)x)[t * 2];
    float4 b = ((const float4*)x)[t * 2 + 1];
    ushort8 u;
    u[0] = f2bf_bits(a.x); u[1] = f2bf_bits(a.y);
    u[2] = f2bf_bits(a.z); u[3] = f2bf_bits(a.w);
    u[4] = f2bf_bits(b.x); u[5] = f2bf_bits(b.y);
    u[6] = f2bf_bits(b.z); u[7] = f2bf_bits(b.w);
    ((ushort8*)xbf)[t] = u;
    int w0 = __builtin_amdgcn_cvt_pk_fp8_f32(a.x, a.y, 0, false);
    w0     = __builtin_amdgcn_cvt_pk_fp8_f32(a.z, a.w, w0, true);
    int w1 = __builtin_amdgcn_cvt_pk_fp8_f32(b.x, b.y, 0, false);
    w1     = __builtin_amdgcn_cvt_pk_fp8_f32(b.z, b.w, w1, true);
    uint2 p; p.x = (unsigned)w0; p.y = (unsigned)w1;
    ((uint2*)x8)[t] = p;
}

// ---------------------------------------------------------------------------
// 2) fused partition: per-block LDS histogram -> in-block scan -> scatter
//    into the block's PRIVATE contiguous region of ebin (blk-major layout).
//    offtbl[blk*NTBL + bin] = global start of (blk,bin) run.
// ---------------------------------------------------------------------------
__global__ __launch_bounds__(512) void part_kernel(const int* __restrict__ ei,
                                                   int* __restrict__ offtbl,
                                                   int* __restrict__ ebin) {
    __shared__ int h[NBINS];   // histogram, then cursors (global positions)
    __shared__ int wsum[8];
    const int tid = threadIdx.x, b = blockIdx.x;
    const int lane = tid & 63, wid = tid >> 6;

    for (int i = tid; i < NBINS; i += 512) h[i] = 0;
    __syncthreads();

    const int4* dsts = (const int4*)(ei + N_EDGES + b * CHUNK);
    for (int i = tid; i < CHUNK / 4; i += 512) {
        int4 d = dsts[i];
        atomicAdd(&h[d.x / BIN_NODES], 1);
        atomicAdd(&h[d.y / BIN_NODES], 1);
        atomicAdd(&h[d.z / BIN_NODES], 1);
        atomicAdd(&h[d.w / BIN_NODES], 1);
    }
    __syncthreads();

    // in-block exclusive scan over 2048 counts (4 per thread)
    const int i0 = tid * 4;
    int v0 = h[i0], v1 = h[i0 + 1], v2 = h[i0 + 2], v3 = h[i0 + 3];
    const int s = v0 + v1 + v2 + v3;
    int incl = s;
    #pragma unroll
    for (int d = 1; d < 64; d <<= 1) {
        int up = __shfl_up(incl, d);
        if (lane >= d) incl += up;
    }
    if (lane == 63) wsum[wid] = incl;
    __syncthreads();
    if (tid == 0) {
        int run = 0;
        #pragma unroll
        for (int i = 0; i < 8; ++i) { int v = wsum[i]; wsum[i] = run; run += v; }
    }
    __syncthreads();
    int run = wsum[wid] + incl - s + b * CHUNK;   // global position
    int* otb = offtbl + (size_t)b * NTBL;
    // write cursors (global positions) back into h, and the table
    h[i0] = run; otb[i0] = run; run += v0;
    h[i0 + 1] = run; otb[i0 + 1] = run; run += v1;
    h[i0 + 2] = run; otb[i0 + 2] = run; run += v2;
    h[i0 + 3] = run; otb[i0 + 3] = run; run += v3;
    if (tid == 0) otb[NBINS] = (b + 1) * CHUNK;
    __syncthreads();

    // scatter pass: private, cursor-sequential writes
    const int4* srcs = (const int4*)(ei + b * CHUNK);
    for (int i = tid; i < CHUNK / 4; i += 512) {
        int4 s4 = srcs[i];
        int4 d4 = dsts[i];
        int bin, ln, pos;
        bin = d4.x / BIN_NODES; ln = d4.x - bin * BIN_NODES;
        pos = atomicAdd(&h[bin], 1); ebin[pos] = s4.x | (ln << 17);
        bin = d4.y / BIN_NODES; ln = d4.y - bin * BIN_NODES;
        pos = atomicAdd(&h[bin], 1); ebin[pos] = s4.y | (ln << 17);
        bin = d4.z / BIN_NODES; ln = d4.z - bin * BIN_NODES;
        pos = atomicAdd(&h[bin], 1); ebin[pos] = s4.z | (ln << 17);
        bin = d4.w / BIN_NODES; ln = d4.w - bin * BIN_NODES;
        pos = atomicAdd(&h[bin], 1); ebin[pos] = s4.w | (ln << 17);
    }
}

// ---------------------------------------------------------------------------
// 3) per-bin aggregation: edges arrive as PBLK short runs per bin.
//    LDS CSR build + fp8 gather-mean (128 B rows).
// ---------------------------------------------------------------------------
#define ACC8(v)                                                             \
    {                                                                       \
        f32x2 f0 = __builtin_amdgcn_cvt_pk_f32_fp8((int)(v).x, false);      \
        f32x2 f1 = __builtin_amdgcn_cvt_pk_f32_fp8((int)(v).x, true);       \
        f32x2 f2 = __builtin_amdgcn_cvt_pk_f32_fp8((int)(v).y, false);      \
        f32x2 f3 = __builtin_amdgcn_cvt_pk_f32_fp8((int)(v).y, true);       \
        acc[0] += f0[0]; acc[1] += f0[1];                                   \
        acc[2] += f1[0]; acc[3] += f1[1];                                   \
        acc[4] += f2[0]; acc[5] += f2[1];                                   \
        acc[6] += f3[0]; acc[7] += f3[1];                                   \
    }

__global__ __launch_bounds__(256) void agg_kernel(
    const unsigned char* __restrict__ x8, const int* __restrict__ offtbl,
    const int* __restrict__ ebin, unsigned short* __restrict__ xbarbf,
    int* __restrict__ degs) {
    __shared__ int lcnt[BIN_NODES];
    __shared__ int loff[BIN_NODES];
    __shared__ int lcur[BIN_NODES];
    __shared__ int lcsr[CSR_MAX];

    const int b = blockIdx.x, tid = threadIdx.x;
    int nb = N_NODES - b * BIN_NODES;
    if (nb <= 0) return;          // trailing empty bins
    if (nb > BIN_NODES) nb = BIN_NODES;

    // this thread's run (one per partition block)
    int st = 0, en = 0;
    if (tid < PBLK) {
        st = offtbl[(size_t)tid * NTBL + b];
        en = offtbl[(size_t)tid * NTBL + b + 1];
    }

    if (tid < BIN_NODES) lcnt[tid] = 0;
    __syncthreads();
    for (int i = st; i < en; ++i)
        atomicAdd(&lcnt[ebin[i] >> 17], 1);
    __syncthreads();

    const int lane = tid & 63, wave = tid >> 6;
    // exclusive scan of 49 counters in wave 0
    if (wave == 0) {
        int c = (lane < BIN_NODES) ? lcnt[lane] : 0;
        int incl = c;
        #pragma unroll
        for (int d = 1; d < 64; d <<= 1) {
            int up = __shfl_up(incl, d);
            if (lane >= d) incl += up;
        }
        if (lane < BIN_NODES) {
            loff[lane] = incl - c;
            lcur[lane] = incl - c;
        }
    }
    __syncthreads();

    for (int i = st; i < en; ++i) {
        int v = ebin[i];
        int pos = atomicAdd(&lcur[v >> 17], 1);
        lcsr[pos] = v & 0x1FFFF;
    }
    __syncthreads();

    const int g = lane >> 4;
    const unsigned c8 = (lane & 15) * 8;   // byte offset in 128 B fp8 row
    for (int ln = wave; ln < nb; ln += 4) {
        const int deg = lcnt[ln];
        const int s0 = loff[ln];
        float acc[8];
        #pragma unroll
        for (int i = 0; i < 8; ++i) acc[i] = 0.f;
        int base = 0;
        const int full16 = deg & ~15;
        for (; base < full16; base += 16) {
            unsigned sA = (unsigned)lcsr[s0 + base + g];
            unsigned sB = (unsigned)lcsr[s0 + base + g + 4];
            unsigned sC = (unsigned)lcsr[s0 + base + g + 8];
            unsigned sD = (unsigned)lcsr[s0 + base + g + 12];
            uint2 va = *(const uint2*)(x8 + ((sA << 7) + c8));
            uint2 vb = *(const uint2*)(x8 + ((sB << 7) + c8));
            uint2 vc = *(const uint2*)(x8 + ((sC << 7) + c8));
            uint2 vd = *(const uint2*)(x8 + ((sD << 7) + c8));
            ACC8(va); ACC8(vb); ACC8(vc); ACC8(vd);
        }
        for (; base < deg; base += 8) {
            int j0 = base + g, j1 = j0 + 4;
            bool pA = j0 < deg, pB = j1 < deg;
            unsigned sA = (unsigned)(pA ? lcsr[s0 + j0] : lcsr[s0]);
            unsigned sB = (unsigned)(pB ? lcsr[s0 + j1] : lcsr[s0]);
            uint2 va = *(const uint2*)(x8 + ((sA << 7) + c8));
            uint2 vb = *(const uint2*)(x8 + ((sB << 7) + c8));
            if (pA) ACC8(va);
            if (pB) ACC8(vb);
        }
        #pragma unroll
        for (int i = 0; i < 8; ++i) {
            acc[i] += __shfl_xor(acc[i], 16);
            acc[i] += __shfl_xor(acc[i], 32);
        }
        const int n = b * BIN_NODES + ln;
        if (lane < 16) {
            float inv = 1.0f / (float)(deg > 0 ? deg : 1);
            ushort8 o;
            #pragma unroll
            for (int i = 0; i < 8; ++i) o[i] = f2bf_bits(acc[i] * inv);
            *(ushort8*)(xbarbf + (size_t)n * FEAT + c8) = o;
        }
        if (lane == 0) degs[n] = deg;
    }
}

// ---------------------------------------------------------------------------
// 4) fused GEMM: out = xbar @ Wl^T + bl*[deg>0] + x @ Wr^T  (A already bf16)
// ---------------------------------------------------------------------------
__global__ __launch_bounds__(256) void gemm_kernel(
    const unsigned short* __restrict__ xbf, const unsigned short* __restrict__ xbarbf,
    const float* __restrict__ Wl, const float* __restrict__ bl,
    const float* __restrict__ Wr, const int* __restrict__ degs,
    float* __restrict__ out) {

    __shared__ unsigned short lM[32][136];
    __shared__ unsigned short lX[32][136];

    const int tid = threadIdx.x;
    const int wave = tid >> 6, lane = tid & 63;
    const int l15 = lane & 15, lhi = lane >> 4;
    const int colbase = wave * 32;

    bf16x8 bB[2][8];
    float biasv[2];
    #pragma unroll
    for (int ct = 0; ct < 2; ++ct) {
        int col = colbase + ct * 16 + l15;
        biasv[ct] = bl[col];
        const float* wl = Wl + (size_t)col * 128;
        const float* wr = Wr + (size_t)col * 128;
        #pragma unroll
        for (int s = 0; s < 4; ++s) {
            int kb = lhi * 8 + s * 32;
            bf16x8 bfr, cfr;
            #pragma unroll
            for (int i = 0; i < 8; ++i) {
                bfr[i] = __builtin_bit_cast(__bf16, f2bf_bits(wl[kb + i]));
                cfr[i] = __builtin_bit_cast(__bf16, f2bf_bits(wr[kb + i]));
            }
            bB[ct][s] = bfr;
            bB[ct][4 + s] = cfr;
        }
    }

    const int ntiles = N_NODES / 32;
    for (int tile = blockIdx.x; tile < ntiles; tile += gridDim.x) {
        const int row0 = tile * 32;
        {
            int r = tid >> 3;
            int c0 = (tid & 7) * 16;
            const unsigned short* sm = xbarbf + (size_t)(row0 + r) * FEAT + c0;
            const unsigned short* sx = xbf + (size_t)(row0 + r) * FEAT + c0;
            *(ushort8*)&lM[r][c0]     = *(const ushort8*)(sm);
            *(ushort8*)&lM[r][c0 + 8] = *(const ushort8*)(sm + 8);
            *(ushort8*)&lX[r][c0]     = *(const ushort8*)(sx);
            *(ushort8*)&lX[r][c0 + 8] = *(const ushort8*)(sx + 8);
        }
        __syncthreads();

        f32x4 acc[2][2];
        #pragma unroll
        for (int rh = 0; rh < 2; ++rh)
            #pragma unroll
            for (int ct = 0; ct < 2; ++ct) acc[rh][ct] = (f32x4){0.f, 0.f, 0.f, 0.f};

        #pragma unroll
        for (int rh = 0; rh < 2; ++rh) {
            int arow = rh * 16 + l15;
            bf16x8 aM[4], aX[4];
            #pragma unroll
            for (int s = 0; s < 4; ++s) {
                aM[s] = __builtin_bit_cast(bf16x8, *(const ushort8*)&lM[arow][lhi * 8 + s * 32]);
                aX[s] = __builtin_bit_cast(bf16x8, *(const ushort8*)&lX[arow][lhi * 8 + s * 32]);
            }
            #pragma unroll
            for (int ct = 0; ct < 2; ++ct) {
                f32x4 a = acc[rh][ct];
                #pragma unroll
                for (int s = 0; s < 4; ++s)
                    a = __builtin_amdgcn_mfma_f32_16x16x32_bf16(aM[s], bB[ct][s], a, 0, 0, 0);
                #pragma unroll
                for (int s = 0; s < 4; ++s)
                    a = __builtin_amdgcn_mfma_f32_16x16x32_bf16(aX[s], bB[ct][4 + s], a, 0, 0, 0);
                acc[rh][ct] = a;
            }
        }

        #pragma unroll
        for (int rh = 0; rh < 2; ++rh)
            #pragma unroll
            for (int ct = 0; ct < 2; ++ct) {
                int col = colbase + ct * 16 + l15;
                #pragma unroll
                for (int j = 0; j < 4; ++j) {
                    int r = row0 + rh * 16 + lhi * 4 + j;
                    float bias = (degs[r] > 0) ? biasv[ct] : 0.f;
                    out[(size_t)r * FEAT + col] = acc[rh][ct][j] + bias;
                }
            }
        __syncthreads();
    }
}

extern "C" void kernel_launch(void* const* d_in, const int* in_sizes, int n_in,
                              void* d_out, int out_size, void* d_ws, size_t ws_size,
                              hipStream_t stream) {
    const float* x  = (const float*)d_in[0];
    const int*   ei = (const int*)d_in[1];
    const float* Wl = (const float*)d_in[2];
    const float* bl = (const float*)d_in[3];
    const float* Wr = (const float*)d_in[4];
    float* out = (float*)d_out;

    unsigned short* xbf    = (unsigned short*)d_ws;                  // 25.6 MB
    unsigned short* xbarbf = xbf + (size_t)N_NODES * FEAT;           // 25.6 MB
    unsigned int* x8       = (unsigned int*)(xbarbf + (size_t)N_NODES * FEAT); // 12.8 MB
    int* degs   = (int*)(x8 + (size_t)N_NODES * FEAT / 4);           // 400 KB
    int* offtbl = degs + N_NODES;                                    // 2.05 MB
    int* ebin   = offtbl + (size_t)PBLK * NTBL;                      // 6.4 MB

    prep_kernel<<<(N_NODES * FEAT / 8 + 255) / 256, 256, 0, stream>>>(x, xbf, x8);
    part_kernel<<<PBLK, 512, 0, stream>>>(ei, offtbl, ebin);
    agg_kernel<<<NBINS, 256, 0, stream>>>((const unsigned char*)x8, offtbl, ebin, xbarbf, degs);
    gemm_kernel<<<1024, 256, 0, stream>>>(xbf, xbarbf, Wl, bl, Wr, degs, out);
}

// Round 10
// 100.860 us; speedup vs baseline: 1.9084x; 1.1501x over previous
//
#include <hip/hip_runtime.h>
#include <hip/hip_bf16.h>

#define N_NODES 100000
#define N_EDGES 1600000
#define FEAT 128
#define NBINS 2048
#define BIN_NODES 49            // 2048*49 = 100352 >= 100000
#define PBLK 250                // partition blocks (each owns CHUNK edges)
#define CHUNK (N_EDGES / PBLK)  // 6400 (exact)
#define NTBL (NBINS + 1)
#define CSR_MAX 1280            // per-bin edges: mean 784, +17 sigma

typedef __bf16 bf16x8 __attribute__((ext_vector_type(8)));
typedef unsigned short ushort8 __attribute__((ext_vector_type(8)));
typedef float f32x4 __attribute__((ext_vector_type(4)));
typedef float f32x2 __attribute__((ext_vector_type(2)));

__device__ __forceinline__ unsigned short f2bf_bits(float f) {
    unsigned u = __builtin_bit_cast(unsigned, f);
    unsigned r = (u + 0x7fffu + ((u >> 16) & 1u)) >> 16;
    return (unsigned short)r;
}

// ---------------------------------------------------------------------------
// 1) x (fp32) -> xbf (bf16 bits) AND x8 (fp8 e4m3, for the gather)
// ---------------------------------------------------------------------------
__global__ void prep_kernel(const float* __restrict__ x,
                            unsigned short* __restrict__ xbf,
                            unsigned int* __restrict__ x8) {
    int t = blockIdx.x * blockDim.x + threadIdx.x;
    if (t >= N_NODES * FEAT / 8) return;
    float4 a = ((const float4*)x)[t * 2];
    float4 b = ((const float4*)x)[t * 2 + 1];
    ushort8 u;
    u[0] = f2bf_bits(a.x); u[1] = f2bf_bits(a.y);
    u[2] = f2bf_bits(a.z); u[3] = f2bf_bits(a.w);
    u[4] = f2bf_bits(b.x); u[5] = f2bf_bits(b.y);
    u[6] = f2bf_bits(b.z); u[7] = f2bf_bits(b.w);
    ((ushort8*)xbf)[t] = u;
    int w0 = __builtin_amdgcn_cvt_pk_fp8_f32(a.x, a.y, 0, false);
    w0     = __builtin_amdgcn_cvt_pk_fp8_f32(a.z, a.w, w0, true);
    int w1 = __builtin_amdgcn_cvt_pk_fp8_f32(b.x, b.y, 0, false);
    w1     = __builtin_amdgcn_cvt_pk_fp8_f32(b.z, b.w, w1, true);
    uint2 p; p.x = (unsigned)w0; p.y = (unsigned)w1;
    ((uint2*)x8)[t] = p;
}

// ---------------------------------------------------------------------------
// 2) fused partition: per-block LDS histogram -> in-block scan -> scatter
//    into the block's PRIVATE contiguous region of ebin (blk-major layout).
//    offtbl[blk*NTBL + bin] = global start of (blk,bin) run.
// ---------------------------------------------------------------------------
__global__ __launch_bounds__(512) void part_kernel(const int* __restrict__ ei,
                                                   int* __restrict__ offtbl,
                                                   int* __restrict__ ebin) {
    __shared__ int h[NBINS];   // histogram, then cursors (global positions)
    __shared__ int wsum[8];
    const int tid = threadIdx.x, b = blockIdx.x;
    const int lane = tid & 63, wid = tid >> 6;

    for (int i = tid; i < NBINS; i += 512) h[i] = 0;
    __syncthreads();

    const int4* dsts = (const int4*)(ei + N_EDGES + b * CHUNK);
    for (int i = tid; i < CHUNK / 4; i += 512) {
        int4 d = dsts[i];
        atomicAdd(&h[d.x / BIN_NODES], 1);
        atomicAdd(&h[d.y / BIN_NODES], 1);
        atomicAdd(&h[d.z / BIN_NODES], 1);
        atomicAdd(&h[d.w / BIN_NODES], 1);
    }
    __syncthreads();

    // in-block exclusive scan over 2048 counts (4 per thread)
    const int i0 = tid * 4;
    int v0 = h[i0], v1 = h[i0 + 1], v2 = h[i0 + 2], v3 = h[i0 + 3];
    const int s = v0 + v1 + v2 + v3;
    int incl = s;
    #pragma unroll
    for (int d = 1; d < 64; d <<= 1) {
        int up = __shfl_up(incl, d);
        if (lane >= d) incl += up;
    }
    if (lane == 63) wsum[wid] = incl;
    __syncthreads();
    if (tid == 0) {
        int run = 0;
        #pragma unroll
        for (int i = 0; i < 8; ++i) { int v = wsum[i]; wsum[i] = run; run += v; }
    }
    __syncthreads();
    int run = wsum[wid] + incl - s + b * CHUNK;   // global position
    int* otb = offtbl + (size_t)b * NTBL;
    // write cursors (global positions) back into h, and the table
    h[i0] = run; otb[i0] = run; run += v0;
    h[i0 + 1] = run; otb[i0 + 1] = run; run += v1;
    h[i0 + 2] = run; otb[i0 + 2] = run; run += v2;
    h[i0 + 3] = run; otb[i0 + 3] = run; run += v3;
    if (tid == 0) otb[NBINS] = (b + 1) * CHUNK;
    __syncthreads();

    // scatter pass: private, cursor-sequential writes
    const int4* srcs = (const int4*)(ei + b * CHUNK);
    for (int i = tid; i < CHUNK / 4; i += 512) {
        int4 s4 = srcs[i];
        int4 d4 = dsts[i];
        int bin, ln, pos;
        bin = d4.x / BIN_NODES; ln = d4.x - bin * BIN_NODES;
        pos = atomicAdd(&h[bin], 1); ebin[pos] = s4.x | (ln << 17);
        bin = d4.y / BIN_NODES; ln = d4.y - bin * BIN_NODES;
        pos = atomicAdd(&h[bin], 1); ebin[pos] = s4.y | (ln << 17);
        bin = d4.z / BIN_NODES; ln = d4.z - bin * BIN_NODES;
        pos = atomicAdd(&h[bin], 1); ebin[pos] = s4.z | (ln << 17);
        bin = d4.w / BIN_NODES; ln = d4.w - bin * BIN_NODES;
        pos = atomicAdd(&h[bin], 1); ebin[pos] = s4.w | (ln << 17);
    }
}

// ---------------------------------------------------------------------------
// 3) per-bin aggregation. XCD-swizzled bin assignment (contiguous 256-bin
//    range per XCD -> ebin/xbar locality in the XCD's L2). Single global
//    read of ebin into LDS staging (lraw) with on-the-fly count; ln-scatter
//    and gather-mean run from LDS.
// ---------------------------------------------------------------------------
#define ACC8(v)                                                             \
    {                                                                       \
        f32x2 f0 = __builtin_amdgcn_cvt_pk_f32_fp8((int)(v).x, false);      \
        f32x2 f1 = __builtin_amdgcn_cvt_pk_f32_fp8((int)(v).x, true);       \
        f32x2 f2 = __builtin_amdgcn_cvt_pk_f32_fp8((int)(v).y, false);      \
        f32x2 f3 = __builtin_amdgcn_cvt_pk_f32_fp8((int)(v).y, true);       \
        acc[0] += f0[0]; acc[1] += f0[1];                                   \
        acc[2] += f1[0]; acc[3] += f1[1];                                   \
        acc[4] += f2[0]; acc[5] += f2[1];                                   \
        acc[6] += f3[0]; acc[7] += f3[1];                                   \
    }

__global__ __launch_bounds__(256) void agg_kernel(
    const unsigned char* __restrict__ x8, const int* __restrict__ offtbl,
    const int* __restrict__ ebin, unsigned short* __restrict__ xbarbf,
    int* __restrict__ degs) {
    __shared__ int lcnt[BIN_NODES];
    __shared__ int loff[BIN_NODES];
    __shared__ int lcur[BIN_NODES];
    __shared__ int lraw[CSR_MAX];
    __shared__ int lcsr[CSR_MAX];
    __shared__ int wtot[4];

    const int bid = blockIdx.x, tid = threadIdx.x;
    // XCD swizzle: XCD (bid&7) owns bins [(bid&7)*256, ...+256)
    const int b = (bid & 7) * (NBINS / 8) + (bid >> 3);
    int nb = N_NODES - b * BIN_NODES;
    if (nb <= 0) return;          // empty trailing bins
    if (nb > BIN_NODES) nb = BIN_NODES;

    const int lane = tid & 63, wave = tid >> 6;

    // this thread's run (one per partition block)
    int st = 0, L = 0;
    if (tid < PBLK) {
        st = offtbl[(size_t)tid * NTBL + b];
        L  = offtbl[(size_t)tid * NTBL + b + 1] - st;
    }
    if (tid < BIN_NODES) lcnt[tid] = 0;

    // 256-thread exclusive scan of run lengths -> LDS staging offset
    int incl = L;
    #pragma unroll
    for (int d = 1; d < 64; d <<= 1) {
        int up = __shfl_up(incl, d);
        if (lane >= d) incl += up;
    }
    if (lane == 63) wtot[wave] = incl;
    __syncthreads();
    int woff = 0;
    #pragma unroll
    for (int w = 0; w < 4; ++w) woff += (w < wave) ? wtot[w] : 0;
    const int pfx = woff + incl - L;

    // single global read of this bin's edges: copy to lraw + count
    for (int i = 0; i < L; ++i) {
        int v = ebin[st + i];
        lraw[pfx + i] = v;
        atomicAdd(&lcnt[v >> 17], 1);
    }
    __syncthreads();

    // exclusive scan of 49 counters in wave 0
    if (wave == 0) {
        int c = (lane < BIN_NODES) ? lcnt[lane] : 0;
        int ic = c;
        #pragma unroll
        for (int d = 1; d < 64; d <<= 1) {
            int up = __shfl_up(ic, d);
            if (lane >= d) ic += up;
        }
        if (lane < BIN_NODES) {
            loff[lane] = ic - c;
            lcur[lane] = ic - c;
        }
    }
    __syncthreads();

    // ln-scatter entirely from LDS
    for (int i = 0; i < L; ++i) {
        int v = lraw[pfx + i];
        int pos = atomicAdd(&lcur[v >> 17], 1);
        lcsr[pos] = v & 0x1FFFF;
    }
    __syncthreads();

    const int g = lane >> 4;
    const unsigned c8 = (lane & 15) * 8;   // byte offset in 128 B fp8 row
    for (int ln = wave; ln < nb; ln += 4) {
        const int deg = lcnt[ln];
        const int s0 = loff[ln];
        float acc[8];
        #pragma unroll
        for (int i = 0; i < 8; ++i) acc[i] = 0.f;
        int base = 0;
        const int full16 = deg & ~15;
        for (; base < full16; base += 16) {
            unsigned sA = (unsigned)lcsr[s0 + base + g];
            unsigned sB = (unsigned)lcsr[s0 + base + g + 4];
            unsigned sC = (unsigned)lcsr[s0 + base + g + 8];
            unsigned sD = (unsigned)lcsr[s0 + base + g + 12];
            uint2 va = *(const uint2*)(x8 + ((sA << 7) + c8));
            uint2 vb = *(const uint2*)(x8 + ((sB << 7) + c8));
            uint2 vc = *(const uint2*)(x8 + ((sC << 7) + c8));
            uint2 vd = *(const uint2*)(x8 + ((sD << 7) + c8));
            ACC8(va); ACC8(vb); ACC8(vc); ACC8(vd);
        }
        for (; base < deg; base += 8) {
            int j0 = base + g, j1 = j0 + 4;
            bool pA = j0 < deg, pB = j1 < deg;
            unsigned sA = (unsigned)(pA ? lcsr[s0 + j0] : lcsr[s0]);
            unsigned sB = (unsigned)(pB ? lcsr[s0 + j1] : lcsr[s0]);
            uint2 va = *(const uint2*)(x8 + ((sA << 7) + c8));
            uint2 vb = *(const uint2*)(x8 + ((sB << 7) + c8));
            if (pA) ACC8(va);
            if (pB) ACC8(vb);
        }
        #pragma unroll
        for (int i = 0; i < 8; ++i) {
            acc[i] += __shfl_xor(acc[i], 16);
            acc[i] += __shfl_xor(acc[i], 32);
        }
        const int n = b * BIN_NODES + ln;
        if (lane < 16) {
            float inv = 1.0f / (float)(deg > 0 ? deg : 1);
            ushort8 o;
            #pragma unroll
            for (int i = 0; i < 8; ++i) o[i] = f2bf_bits(acc[i] * inv);
            *(ushort8*)(xbarbf + (size_t)n * FEAT + c8) = o;
        }
        if (lane == 0) degs[n] = deg;
    }
}

// ---------------------------------------------------------------------------
// 4) fused GEMM: out = xbar @ Wl^T + bl*[deg>0] + x @ Wr^T  (A already bf16)
// ---------------------------------------------------------------------------
__global__ __launch_bounds__(256) void gemm_kernel(
    const unsigned short* __restrict__ xbf, const unsigned short* __restrict__ xbarbf,
    const float* __restrict__ Wl, const float* __restrict__ bl,
    const float* __restrict__ Wr, const int* __restrict__ degs,
    float* __restrict__ out) {

    __shared__ unsigned short lM[32][136];
    __shared__ unsigned short lX[32][136];

    const int tid = threadIdx.x;
    const int wave = tid >> 6, lane = tid & 63;
    const int l15 = lane & 15, lhi = lane >> 4;
    const int colbase = wave * 32;

    bf16x8 bB[2][8];
    float biasv[2];
    #pragma unroll
    for (int ct = 0; ct < 2; ++ct) {
        int col = colbase + ct * 16 + l15;
        biasv[ct] = bl[col];
        const float* wl = Wl + (size_t)col * 128;
        const float* wr = Wr + (size_t)col * 128;
        #pragma unroll
        for (int s = 0; s < 4; ++s) {
            int kb = lhi * 8 + s * 32;
            bf16x8 bfr, cfr;
            #pragma unroll
            for (int i = 0; i < 8; ++i) {
                bfr[i] = __builtin_bit_cast(__bf16, f2bf_bits(wl[kb + i]));
                cfr[i] = __builtin_bit_cast(__bf16, f2bf_bits(wr[kb + i]));
            }
            bB[ct][s] = bfr;
            bB[ct][4 + s] = cfr;
        }
    }

    const int ntiles = N_NODES / 32;
    for (int tile = blockIdx.x; tile < ntiles; tile += gridDim.x) {
        const int row0 = tile * 32;
        {
            int r = tid >> 3;
            int c0 = (tid & 7) * 16;
            const unsigned short* sm = xbarbf + (size_t)(row0 + r) * FEAT + c0;
            const unsigned short* sx = xbf + (size_t)(row0 + r) * FEAT + c0;
            *(ushort8*)&lM[r][c0]     = *(const ushort8*)(sm);
            *(ushort8*)&lM[r][c0 + 8] = *(const ushort8*)(sm + 8);
            *(ushort8*)&lX[r][c0]     = *(const ushort8*)(sx);
            *(ushort8*)&lX[r][c0 + 8] = *(const ushort8*)(sx + 8);
        }
        __syncthreads();

        f32x4 acc[2][2];
        #pragma unroll
        for (int rh = 0; rh < 2; ++rh)
            #pragma unroll
            for (int ct = 0; ct < 2; ++ct) acc[rh][ct] = (f32x4){0.f, 0.f, 0.f, 0.f};

        #pragma unroll
        for (int rh = 0; rh < 2; ++rh) {
            int arow = rh * 16 + l15;
            bf16x8 aM[4], aX[4];
            #pragma unroll
            for (int s = 0; s < 4; ++s) {
                aM[s] = __builtin_bit_cast(bf16x8, *(const ushort8*)&lM[arow][lhi * 8 + s * 32]);
                aX[s] = __builtin_bit_cast(bf16x8, *(const ushort8*)&lX[arow][lhi * 8 + s * 32]);
            }
            #pragma unroll
            for (int ct = 0; ct < 2; ++ct) {
                f32x4 a = acc[rh][ct];
                #pragma unroll
                for (int s = 0; s < 4; ++s)
                    a = __builtin_amdgcn_mfma_f32_16x16x32_bf16(aM[s], bB[ct][s], a, 0, 0, 0);
                #pragma unroll
                for (int s = 0; s < 4; ++s)
                    a = __builtin_amdgcn_mfma_f32_16x16x32_bf16(aX[s], bB[ct][4 + s], a, 0, 0, 0);
                acc[rh][ct] = a;
            }
        }

        #pragma unroll
        for (int rh = 0; rh < 2; ++rh)
            #pragma unroll
            for (int ct = 0; ct < 2; ++ct) {
                int col = colbase + ct * 16 + l15;
                #pragma unroll
                for (int j = 0; j < 4; ++j) {
                    int r = row0 + rh * 16 + lhi * 4 + j;
                    float bias = (degs[r] > 0) ? biasv[ct] : 0.f;
                    out[(size_t)r * FEAT + col] = acc[rh][ct][j] + bias;
                }
            }
        __syncthreads();
    }
}

extern "C" void kernel_launch(void* const* d_in, const int* in_sizes, int n_in,
                              void* d_out, int out_size, void* d_ws, size_t ws_size,
                              hipStream_t stream) {
    const float* x  = (const float*)d_in[0];
    const int*   ei = (const int*)d_in[1];
    const float* Wl = (const float*)d_in[2];
    const float* bl = (const float*)d_in[3];
    const float* Wr = (const float*)d_in[4];
    float* out = (float*)d_out;

    unsigned short* xbf    = (unsigned short*)d_ws;                  // 25.6 MB
    unsigned short* xbarbf = xbf + (size_t)N_NODES * FEAT;           // 25.6 MB
    unsigned int* x8       = (unsigned int*)(xbarbf + (size_t)N_NODES * FEAT); // 12.8 MB
    int* degs   = (int*)(x8 + (size_t)N_NODES * FEAT / 4);           // 400 KB
    int* offtbl = degs + N_NODES;                                    // 2.05 MB
    int* ebin   = offtbl + (size_t)PBLK * NTBL;                      // 6.4 MB

    prep_kernel<<<(N_NODES * FEAT / 8 + 255) / 256, 256, 0, stream>>>(x, xbf, x8);
    part_kernel<<<PBLK, 512, 0, stream>>>(ei, offtbl, ebin);
    agg_kernel<<<NBINS, 256, 0, stream>>>((const unsigned char*)x8, offtbl, ebin, xbarbf, degs);
    gemm_kernel<<<1024, 256, 0, stream>>>(xbf, xbarbf, Wl, bl, Wr, degs, out);
}

// Round 11
// 96.861 us; speedup vs baseline: 1.9872x; 1.0413x over previous
//
#include <hip/hip_runtime.h>
#include <hip/hip_bf16.h>

#define N_NODES 100000
#define N_EDGES 1600000
#define FEAT 128
#define NBINS 2048
#define BIN_NODES 49            // 2048*49 = 100352 >= 100000
#define PBLK 250                // partition blocks (each owns CHUNK edges)
#define CHUNK (N_EDGES / PBLK)  // 6400 (exact)
#define NTBL (NBINS + 1)
#define CSR_MAX 1280            // per-bin edges: mean 784, +17 sigma
#define PREP_BLOCKS (N_NODES * FEAT / 8 / 512)  // 3125 (exact)

typedef __bf16 bf16x8 __attribute__((ext_vector_type(8)));
typedef unsigned short ushort8 __attribute__((ext_vector_type(8)));
typedef float f32x4 __attribute__((ext_vector_type(4)));
typedef float f32x2 __attribute__((ext_vector_type(2)));

__device__ __forceinline__ unsigned short f2bf_bits(float f) {
    unsigned u = __builtin_bit_cast(unsigned, f);
    unsigned r = (u + 0x7fffu + ((u >> 16) & 1u)) >> 16;
    return (unsigned short)r;
}

// ---------------------------------------------------------------------------
// 1) fused prep + partition (independent work, role-split by blockIdx).
//    Blocks [0, PBLK): edge partition (LDS hist -> scan -> private scatter).
//    Blocks [PBLK, PBLK+PREP_BLOCKS): x -> xbf (bf16) and x8 (fp8 e4m3).
// ---------------------------------------------------------------------------
__global__ __launch_bounds__(512) void preppart_kernel(
    const float* __restrict__ x, unsigned short* __restrict__ xbf,
    unsigned int* __restrict__ x8, const int* __restrict__ ei,
    int* __restrict__ offtbl, int* __restrict__ ebin) {
    __shared__ int h[NBINS];   // histogram, then cursors (global positions)
    __shared__ int wsum[8];
    const int tid = threadIdx.x;

    if (blockIdx.x >= PBLK) {
        // ---- prep role ----
        int t = (blockIdx.x - PBLK) * 512 + tid;
        float4 a = ((const float4*)x)[t * 2];
        float4 b = ((const float4*)x)[t * 2 + 1];
        ushort8 u;
        u[0] = f2bf_bits(a.x); u[1] = f2bf_bits(a.y);
        u[2] = f2bf_bits(a.z); u[3] = f2bf_bits(a.w);
        u[4] = f2bf_bits(b.x); u[5] = f2bf_bits(b.y);
        u[6] = f2bf_bits(b.z); u[7] = f2bf_bits(b.w);
        ((ushort8*)xbf)[t] = u;
        int w0 = __builtin_amdgcn_cvt_pk_fp8_f32(a.x, a.y, 0, false);
        w0     = __builtin_amdgcn_cvt_pk_fp8_f32(a.z, a.w, w0, true);
        int w1 = __builtin_amdgcn_cvt_pk_fp8_f32(b.x, b.y, 0, false);
        w1     = __builtin_amdgcn_cvt_pk_fp8_f32(b.z, b.w, w1, true);
        uint2 p; p.x = (unsigned)w0; p.y = (unsigned)w1;
        ((uint2*)x8)[t] = p;
        return;
    }

    // ---- partition role ----
    const int b = blockIdx.x;
    const int lane = tid & 63, wid = tid >> 6;

    for (int i = tid; i < NBINS; i += 512) h[i] = 0;
    __syncthreads();

    const int4* dsts = (const int4*)(ei + N_EDGES + b * CHUNK);
    for (int i = tid; i < CHUNK / 4; i += 512) {
        int4 d = dsts[i];
        atomicAdd(&h[d.x / BIN_NODES], 1);
        atomicAdd(&h[d.y / BIN_NODES], 1);
        atomicAdd(&h[d.z / BIN_NODES], 1);
        atomicAdd(&h[d.w / BIN_NODES], 1);
    }
    __syncthreads();

    // in-block exclusive scan over 2048 counts (4 per thread)
    const int i0 = tid * 4;
    int v0 = h[i0], v1 = h[i0 + 1], v2 = h[i0 + 2], v3 = h[i0 + 3];
    const int s = v0 + v1 + v2 + v3;
    int incl = s;
    #pragma unroll
    for (int d = 1; d < 64; d <<= 1) {
        int up = __shfl_up(incl, d);
        if (lane >= d) incl += up;
    }
    if (lane == 63) wsum[wid] = incl;
    __syncthreads();
    if (tid == 0) {
        int run = 0;
        #pragma unroll
        for (int i = 0; i < 8; ++i) { int v = wsum[i]; wsum[i] = run; run += v; }
    }
    __syncthreads();
    int run = wsum[wid] + incl - s + b * CHUNK;   // global position
    int* otb = offtbl + (size_t)b * NTBL;
    h[i0] = run; otb[i0] = run; run += v0;
    h[i0 + 1] = run; otb[i0 + 1] = run; run += v1;
    h[i0 + 2] = run; otb[i0 + 2] = run; run += v2;
    h[i0 + 3] = run; otb[i0 + 3] = run; run += v3;
    if (tid == 0) otb[NBINS] = (b + 1) * CHUNK;
    __syncthreads();

    // scatter pass: private, cursor-sequential writes
    const int4* srcs = (const int4*)(ei + b * CHUNK);
    for (int i = tid; i < CHUNK / 4; i += 512) {
        int4 s4 = srcs[i];
        int4 d4 = dsts[i];
        int bin, ln, pos;
        bin = d4.x / BIN_NODES; ln = d4.x - bin * BIN_NODES;
        pos = atomicAdd(&h[bin], 1); ebin[pos] = s4.x | (ln << 17);
        bin = d4.y / BIN_NODES; ln = d4.y - bin * BIN_NODES;
        pos = atomicAdd(&h[bin], 1); ebin[pos] = s4.y | (ln << 17);
        bin = d4.z / BIN_NODES; ln = d4.z - bin * BIN_NODES;
        pos = atomicAdd(&h[bin], 1); ebin[pos] = s4.z | (ln << 17);
        bin = d4.w / BIN_NODES; ln = d4.w - bin * BIN_NODES;
        pos = atomicAdd(&h[bin], 1); ebin[pos] = s4.w | (ln << 17);
    }
}

// ---------------------------------------------------------------------------
// 2) per-bin aggregation. XCD-swizzled bins; single global read of ebin into
//    LDS staging; fp8 gather with PACKED f32x2 accumulation (v_pk_add_f32).
// ---------------------------------------------------------------------------
#define ACC8(v)                                                             \
    {                                                                       \
        acc2[0] += __builtin_amdgcn_cvt_pk_f32_fp8((int)(v).x, false);      \
        acc2[1] += __builtin_amdgcn_cvt_pk_f32_fp8((int)(v).x, true);       \
        acc2[2] += __builtin_amdgcn_cvt_pk_f32_fp8((int)(v).y, false);      \
        acc2[3] += __builtin_amdgcn_cvt_pk_f32_fp8((int)(v).y, true);       \
    }

__global__ __launch_bounds__(256) void agg_kernel(
    const unsigned char* __restrict__ x8, const int* __restrict__ offtbl,
    const int* __restrict__ ebin, unsigned short* __restrict__ xbarbf,
    int* __restrict__ degs) {
    __shared__ int lcnt[BIN_NODES];
    __shared__ int loff[BIN_NODES];
    __shared__ int lcur[BIN_NODES];
    __shared__ int lraw[CSR_MAX];
    __shared__ int lcsr[CSR_MAX];
    __shared__ int wtot[4];

    const int bid = blockIdx.x, tid = threadIdx.x;
    // XCD swizzle: XCD (bid&7) owns bins [(bid&7)*256, ...+256)
    const int b = (bid & 7) * (NBINS / 8) + (bid >> 3);
    int nb = N_NODES - b * BIN_NODES;
    if (nb <= 0) return;          // empty trailing bins
    if (nb > BIN_NODES) nb = BIN_NODES;

    const int lane = tid & 63, wave = tid >> 6;

    // this thread's run (one per partition block)
    int st = 0, L = 0;
    if (tid < PBLK) {
        st = offtbl[(size_t)tid * NTBL + b];
        L  = offtbl[(size_t)tid * NTBL + b + 1] - st;
    }
    if (tid < BIN_NODES) lcnt[tid] = 0;

    // 256-thread exclusive scan of run lengths -> LDS staging offset
    int incl = L;
    #pragma unroll
    for (int d = 1; d < 64; d <<= 1) {
        int up = __shfl_up(incl, d);
        if (lane >= d) incl += up;
    }
    if (lane == 63) wtot[wave] = incl;
    __syncthreads();
    int woff = 0;
    #pragma unroll
    for (int w = 0; w < 4; ++w) woff += (w < wave) ? wtot[w] : 0;
    const int pfx = woff + incl - L;

    // single global read of this bin's edges: copy to lraw + count
    for (int i = 0; i < L; ++i) {
        int v = ebin[st + i];
        lraw[pfx + i] = v;
        atomicAdd(&lcnt[v >> 17], 1);
    }
    __syncthreads();

    // exclusive scan of 49 counters in wave 0
    if (wave == 0) {
        int c = (lane < BIN_NODES) ? lcnt[lane] : 0;
        int ic = c;
        #pragma unroll
        for (int d = 1; d < 64; d <<= 1) {
            int up = __shfl_up(ic, d);
            if (lane >= d) ic += up;
        }
        if (lane < BIN_NODES) {
            loff[lane] = ic - c;
            lcur[lane] = ic - c;
        }
    }
    __syncthreads();

    // ln-scatter entirely from LDS
    for (int i = 0; i < L; ++i) {
        int v = lraw[pfx + i];
        int pos = atomicAdd(&lcur[v >> 17], 1);
        lcsr[pos] = v & 0x1FFFF;
    }
    __syncthreads();

    const int g = lane >> 4;
    const unsigned c8 = (lane & 15) * 8;   // byte offset in 128 B fp8 row
    for (int ln = wave; ln < nb; ln += 4) {
        const int deg = lcnt[ln];
        const int s0 = loff[ln];
        f32x2 acc2[4];
        #pragma unroll
        for (int i = 0; i < 4; ++i) acc2[i] = (f32x2){0.f, 0.f};
        int base = 0;
        const int full16 = deg & ~15;
        for (; base < full16; base += 16) {
            unsigned sA = (unsigned)lcsr[s0 + base + g];
            unsigned sB = (unsigned)lcsr[s0 + base + g + 4];
            unsigned sC = (unsigned)lcsr[s0 + base + g + 8];
            unsigned sD = (unsigned)lcsr[s0 + base + g + 12];
            uint2 va = *(const uint2*)(x8 + ((sA << 7) + c8));
            uint2 vb = *(const uint2*)(x8 + ((sB << 7) + c8));
            uint2 vc = *(const uint2*)(x8 + ((sC << 7) + c8));
            uint2 vd = *(const uint2*)(x8 + ((sD << 7) + c8));
            ACC8(va); ACC8(vb); ACC8(vc); ACC8(vd);
        }
        for (; base < deg; base += 8) {
            int j0 = base + g, j1 = j0 + 4;
            bool pA = j0 < deg, pB = j1 < deg;
            unsigned sA = (unsigned)(pA ? lcsr[s0 + j0] : lcsr[s0]);
            unsigned sB = (unsigned)(pB ? lcsr[s0 + j1] : lcsr[s0]);
            uint2 va = *(const uint2*)(x8 + ((sA << 7) + c8));
            uint2 vb = *(const uint2*)(x8 + ((sB << 7) + c8));
            if (pA) ACC8(va);
            if (pB) ACC8(vb);
        }
        #pragma unroll
        for (int i = 0; i < 4; ++i) {
            #pragma unroll
            for (int k = 0; k < 2; ++k) {
                acc2[i][k] += __shfl_xor(acc2[i][k], 16);
                acc2[i][k] += __shfl_xor(acc2[i][k], 32);
            }
        }
        const int n = b * BIN_NODES + ln;
        if (lane < 16) {
            float inv = 1.0f / (float)(deg > 0 ? deg : 1);
            ushort8 o;
            #pragma unroll
            for (int i = 0; i < 4; ++i) {
                o[2 * i]     = f2bf_bits(acc2[i][0] * inv);
                o[2 * i + 1] = f2bf_bits(acc2[i][1] * inv);
            }
            *(ushort8*)(xbarbf + (size_t)n * FEAT + c8) = o;
        }
        if (lane == 0) degs[n] = deg;
    }
}

// ---------------------------------------------------------------------------
// 3) fused GEMM: out = xbar @ Wl^T + bl*[deg>0] + x @ Wr^T  (A already bf16)
// ---------------------------------------------------------------------------
__global__ __launch_bounds__(256) void gemm_kernel(
    const unsigned short* __restrict__ xbf, const unsigned short* __restrict__ xbarbf,
    const float* __restrict__ Wl, const float* __restrict__ bl,
    const float* __restrict__ Wr, const int* __restrict__ degs,
    float* __restrict__ out) {

    __shared__ unsigned short lM[32][136];
    __shared__ unsigned short lX[32][136];

    const int tid = threadIdx.x;
    const int wave = tid >> 6, lane = tid & 63;
    const int l15 = lane & 15, lhi = lane >> 4;
    const int colbase = wave * 32;

    bf16x8 bB[2][8];
    float biasv[2];
    #pragma unroll
    for (int ct = 0; ct < 2; ++ct) {
        int col = colbase + ct * 16 + l15;
        biasv[ct] = bl[col];
        const float* wl = Wl + (size_t)col * 128;
        const float* wr = Wr + (size_t)col * 128;
        #pragma unroll
        for (int s = 0; s < 4; ++s) {
            int kb = lhi * 8 + s * 32;
            bf16x8 bfr, cfr;
            #pragma unroll
            for (int i = 0; i < 8; ++i) {
                bfr[i] = __builtin_bit_cast(__bf16, f2bf_bits(wl[kb + i]));
                cfr[i] = __builtin_bit_cast(__bf16, f2bf_bits(wr[kb + i]));
            }
            bB[ct][s] = bfr;
            bB[ct][4 + s] = cfr;
        }
    }

    const int ntiles = N_NODES / 32;
    for (int tile = blockIdx.x; tile < ntiles; tile += gridDim.x) {
        const int row0 = tile * 32;
        {
            int r = tid >> 3;
            int c0 = (tid & 7) * 16;
            const unsigned short* sm = xbarbf + (size_t)(row0 + r) * FEAT + c0;
            const unsigned short* sx = xbf + (size_t)(row0 + r) * FEAT + c0;
            *(ushort8*)&lM[r][c0]     = *(const ushort8*)(sm);
            *(ushort8*)&lM[r][c0 + 8] = *(const ushort8*)(sm + 8);
            *(ushort8*)&lX[r][c0]     = *(const ushort8*)(sx);
            *(ushort8*)&lX[r][c0 + 8] = *(const ushort8*)(sx + 8);
        }
        __syncthreads();

        f32x4 acc[2][2];
        #pragma unroll
        for (int rh = 0; rh < 2; ++rh)
            #pragma unroll
            for (int ct = 0; ct < 2; ++ct) acc[rh][ct] = (f32x4){0.f, 0.f, 0.f, 0.f};

        #pragma unroll
        for (int rh = 0; rh < 2; ++rh) {
            int arow = rh * 16 + l15;
            bf16x8 aM[4], aX[4];
            #pragma unroll
            for (int s = 0; s < 4; ++s) {
                aM[s] = __builtin_bit_cast(bf16x8, *(const ushort8*)&lM[arow][lhi * 8 + s * 32]);
                aX[s] = __builtin_bit_cast(bf16x8, *(const ushort8*)&lX[arow][lhi * 8 + s * 32]);
            }
            #pragma unroll
            for (int ct = 0; ct < 2; ++ct) {
                f32x4 a = acc[rh][ct];
                #pragma unroll
                for (int s = 0; s < 4; ++s)
                    a = __builtin_amdgcn_mfma_f32_16x16x32_bf16(aM[s], bB[ct][s], a, 0, 0, 0);
                #pragma unroll
                for (int s = 0; s < 4; ++s)
                    a = __builtin_amdgcn_mfma_f32_16x16x32_bf16(aX[s], bB[ct][4 + s], a, 0, 0, 0);
                acc[rh][ct] = a;
            }
        }

        #pragma unroll
        for (int rh = 0; rh < 2; ++rh)
            #pragma unroll
            for (int ct = 0; ct < 2; ++ct) {
                int col = colbase + ct * 16 + l15;
                #pragma unroll
                for (int j = 0; j < 4; ++j) {
                    int r = row0 + rh * 16 + lhi * 4 + j;
                    float bias = (degs[r] > 0) ? biasv[ct] : 0.f;
                    out[(size_t)r * FEAT + col] = acc[rh][ct][j] + bias;
                }
            }
        __syncthreads();
    }
}

extern "C" void kernel_launch(void* const* d_in, const int* in_sizes, int n_in,
                              void* d_out, int out_size, void* d_ws, size_t ws_size,
                              hipStream_t stream) {
    const float* x  = (const float*)d_in[0];
    const int*   ei = (const int*)d_in[1];
    const float* Wl = (const float*)d_in[2];
    const float* bl = (const float*)d_in[3];
    const float* Wr = (const float*)d_in[4];
    float* out = (float*)d_out;

    unsigned short* xbf    = (unsigned short*)d_ws;                  // 25.6 MB
    unsigned short* xbarbf = xbf + (size_t)N_NODES * FEAT;           // 25.6 MB
    unsigned int* x8       = (unsigned int*)(xbarbf + (size_t)N_NODES * FEAT); // 12.8 MB
    int* degs   = (int*)(x8 + (size_t)N_NODES * FEAT / 4);           // 400 KB
    int* offtbl = degs + N_NODES;                                    // 2.05 MB
    int* ebin   = offtbl + (size_t)PBLK * NTBL;                      // 6.4 MB

    preppart_kernel<<<PBLK + PREP_BLOCKS, 512, 0, stream>>>(x, xbf, x8, ei, offtbl, ebin);
    agg_kernel<<<NBINS, 256, 0, stream>>>((const unsigned char*)x8, offtbl, ebin, xbarbf, degs);
    gemm_kernel<<<1024, 256, 0, stream>>>(xbf, xbarbf, Wl, bl, Wr, degs, out);
}